// Round 1
// baseline (4498.021 us; speedup 1.0000x reference)
//
#include <hip/hip_runtime.h>
#include <math.h>

#define NE 256
#define DD 256
#define NH 4
#define DH 64
#define NL 2
#define P_TOT 32640          // NE*(NE-1)/2
#define NCHUNK 4
#define PC (P_TOT / NCHUNK)  // 8160 pairs per chunk
#define MC (2 * PC)          // 16320 rows per chunk (divisible by 64)

// ---------------- small helpers ----------------
__global__ void idx_k(int* __restrict__ ip, int* __restrict__ jp) {
    int i = threadIdx.x;  // 0..255
    int base = i * 255 - (i * (i - 1)) / 2;
    for (int j = i + 1; j < NE; ++j) {
        ip[base + j - i - 1] = i;
        jp[base + j - i - 1] = j;
    }
}

__global__ void zero_k(float* __restrict__ acc) {
    if (threadIdx.x < 2) acc[threadIdx.x] = 0.f;
}

// ---------------- input embedding: h = feat @ W_in ----------------
__global__ __launch_bounds__(256) void embed_k(
    const float* __restrict__ el, const float* __restrict__ Win,
    const int* __restrict__ ip, const int* __restrict__ jp,
    float* __restrict__ h, int P0) {
    int r = blockIdx.x;        // local row, 0..MC-1
    int n = threadIdx.x;       // 0..255
    int gp = P0 + (r >> 1);
    int e = (r & 1) ? jp[gp] : ip[gp];
    float th = el[2 * e], ph = el[2 * e + 1];
    float st = sinf(th);
    float f0 = cosf(th), f1 = st * cosf(ph), f2 = st * sinf(ph);
    h[(size_t)r * DD + n] = f0 * Win[n] + f1 * Win[DD + n] + f2 * Win[2 * DD + n];
}

// ---------------- fp32 tiled GEMM: C = A@B (+bias) (+residual) ----------------
// A: [MC,256], B: [256,256] row-major, C: [MC,256]
template <bool BIAS, bool RES>
__global__ __launch_bounds__(256) void gemm_k(
    const float* __restrict__ A, const float* __restrict__ B,
    const float* __restrict__ bias, const float* __restrict__ Rm,
    float* __restrict__ C) {
    __shared__ float As[16][68];
    __shared__ float Bs[16][68];
    int t = threadIdx.x;
    int tm = t >> 4, tn = t & 15;
    int row0 = blockIdx.x * 64, col0 = blockIdx.y * 64;
    float acc[4][4] = {};
    for (int kt = 0; kt < 16; ++kt) {
        int k0 = kt * 16;
        {
            int r = t >> 2, kk = (t & 3) * 4;
            const float4 av = *(const float4*)(A + (size_t)(row0 + r) * DD + k0 + kk);
            As[kk + 0][r] = av.x; As[kk + 1][r] = av.y;
            As[kk + 2][r] = av.z; As[kk + 3][r] = av.w;
        }
        {
            int n = t & 63, kb = t >> 6;
#pragma unroll
            for (int u = 0; u < 4; ++u)
                Bs[kb + 4 * u][n] = B[(size_t)(k0 + kb + 4 * u) * DD + col0 + n];
        }
        __syncthreads();
#pragma unroll
        for (int kk = 0; kk < 16; ++kk) {
            float av0 = As[kk][tm * 4 + 0], av1 = As[kk][tm * 4 + 1];
            float av2 = As[kk][tm * 4 + 2], av3 = As[kk][tm * 4 + 3];
            float bv0 = Bs[kk][tn * 4 + 0], bv1 = Bs[kk][tn * 4 + 1];
            float bv2 = Bs[kk][tn * 4 + 2], bv3 = Bs[kk][tn * 4 + 3];
            acc[0][0] += av0 * bv0; acc[0][1] += av0 * bv1; acc[0][2] += av0 * bv2; acc[0][3] += av0 * bv3;
            acc[1][0] += av1 * bv0; acc[1][1] += av1 * bv1; acc[1][2] += av1 * bv2; acc[1][3] += av1 * bv3;
            acc[2][0] += av2 * bv0; acc[2][1] += av2 * bv1; acc[2][2] += av2 * bv2; acc[2][3] += av2 * bv3;
            acc[3][0] += av3 * bv0; acc[3][1] += av3 * bv1; acc[3][2] += av3 * bv2; acc[3][3] += av3 * bv3;
        }
        __syncthreads();
    }
#pragma unroll
    for (int i2 = 0; i2 < 4; ++i2) {
        int row = row0 + tm * 4 + i2;
#pragma unroll
        for (int j2 = 0; j2 < 4; ++j2) {
            int col = col0 + tn * 4 + j2;
            float v = acc[i2][j2];
            if (BIAS) v += bias[col];
            if (RES) v += Rm[(size_t)row * DD + col];
            C[(size_t)row * DD + col] = v;
        }
    }
}

// ---------------- attention (seq=2), one wave per (pair, head) ----------------
// reads q (in qo), k, v; writes o in-place over q.
__global__ __launch_bounds__(256) void attn_k(
    float* qo, const float* __restrict__ km, const float* __restrict__ vm) {
    int wid = threadIdx.x >> 6, lane = threadIdx.x & 63;
    int gw = blockIdx.x * 4 + wid;   // 0 .. PC*4-1
    int p = gw >> 2, hh = gw & 3;
    size_t r0 = (size_t)(2 * p) * DD + hh * DH + lane;
    size_t r1 = r0 + DD;
    float q0 = qo[r0] * 0.125f, q1 = qo[r1] * 0.125f;
    float k0 = km[r0], k1 = km[r1];
    float v0 = vm[r0], v1 = vm[r1];
    float s00 = q0 * k0, s01 = q0 * k1, s10 = q1 * k0, s11 = q1 * k1;
#pragma unroll
    for (int off = 32; off; off >>= 1) {
        s00 += __shfl_xor(s00, off, 64);
        s01 += __shfl_xor(s01, off, 64);
        s10 += __shfl_xor(s10, off, 64);
        s11 += __shfl_xor(s11, off, 64);
    }
    float m0 = fmaxf(s00, s01), m1 = fmaxf(s10, s11);
    float e00 = expf(s00 - m0), e01 = expf(s01 - m0);
    float e10 = expf(s10 - m1), e11 = expf(s11 - m1);
    float i0 = 1.f / (e00 + e01), i1 = 1.f / (e10 + e11);
    float o0 = (e00 * i0) * v0 + (e01 * i0) * v1;
    float o1 = (e10 * i1) * v0 + (e11 * i1) * v1;
    qo[r0] = o0;
    qo[r1] = o1;
}

// ---------------- layernorm variants (wave per row) ----------------
__global__ __launch_bounds__(256) void ln_a_k(
    const float* __restrict__ X, float* __restrict__ Hm,
    const float* __restrict__ sc, const float* __restrict__ bi) {
    int wid = threadIdx.x >> 6, lane = threadIdx.x & 63;
    int r = blockIdx.x * 4 + wid;
    float x[4]; float sum = 0.f, sq = 0.f;
#pragma unroll
    for (int u = 0; u < 4; ++u) {
        x[u] = X[(size_t)r * DD + u * 64 + lane];
        sum += x[u]; sq += x[u] * x[u];
    }
#pragma unroll
    for (int off = 32; off; off >>= 1) {
        sum += __shfl_xor(sum, off, 64);
        sq += __shfl_xor(sq, off, 64);
    }
    float m = sum * (1.f / 256.f);
    float var = sq * (1.f / 256.f) - m * m;
    float rs = rsqrtf(var + 1e-5f);
#pragma unroll
    for (int u = 0; u < 4; ++u) {
        int d = u * 64 + lane;
        Hm[(size_t)r * DD + d] = (x[u] - m) * rs * sc[d] + bi[d];
    }
}

// h = LN(h + tanh(T)) in place
__global__ __launch_bounds__(256) void ln_b_k(
    float* Hm, const float* __restrict__ T,
    const float* __restrict__ sc, const float* __restrict__ bi) {
    int wid = threadIdx.x >> 6, lane = threadIdx.x & 63;
    int r = blockIdx.x * 4 + wid;
    float x[4]; float sum = 0.f, sq = 0.f;
#pragma unroll
    for (int u = 0; u < 4; ++u) {
        size_t idx = (size_t)r * DD + u * 64 + lane;
        x[u] = Hm[idx] + tanhf(T[idx]);
        sum += x[u]; sq += x[u] * x[u];
    }
#pragma unroll
    for (int off = 32; off; off >>= 1) {
        sum += __shfl_xor(sum, off, 64);
        sq += __shfl_xor(sq, off, 64);
    }
    float m = sum * (1.f / 256.f);
    float var = sq * (1.f / 256.f) - m * m;
    float rs = rsqrtf(var + 1e-5f);
#pragma unroll
    for (int u = 0; u < 4; ++u) {
        int d = u * 64 + lane;
        Hm[(size_t)r * DD + d] = (x[u] - m) * rs * sc[d] + bi[d];
    }
}

// ---------------- per-pair orbitals + 2x2 det ----------------
__global__ __launch_bounds__(256) void orb_k(
    const float* __restrict__ h, const float* __restrict__ Wr, const float* __restrict__ Wi,
    const float* __restrict__ el, const int* __restrict__ ip, const int* __restrict__ jp,
    float2* __restrict__ porb, int P0) {
    int wid = threadIdx.x >> 6, lane = threadIdx.x & 63;
    int p = blockIdx.x * 4 + wid;  // local pair
    const float* h0 = h + (size_t)(2 * p) * DD;
    float s[8] = {0, 0, 0, 0, 0, 0, 0, 0};
#pragma unroll
    for (int u = 0; u < 4; ++u) {
        int d = u * 64 + lane;
        float x0 = h0[d], x1 = h0[DD + d];
        float wr0 = Wr[2 * d], wr1 = Wr[2 * d + 1];
        float wi0 = Wi[2 * d], wi1 = Wi[2 * d + 1];
        s[0] += x0 * wr0; s[1] += x0 * wi0; s[2] += x0 * wr1; s[3] += x0 * wi1;
        s[4] += x1 * wr0; s[5] += x1 * wi0; s[6] += x1 * wr1; s[7] += x1 * wi1;
    }
#pragma unroll
    for (int off = 32; off; off >>= 1) {
#pragma unroll
        for (int q2 = 0; q2 < 8; ++q2) s[q2] += __shfl_xor(s[q2], off, 64);
    }
    if (lane == 0) {
        int gp = P0 + p;
        int i = ip[gp], j = jp[gp];
        float thi = el[2 * i], phi_ = el[2 * i + 1];
        float thj = el[2 * j], phj = el[2 * j + 1];
        float chi = cosf(thi * 0.5f), shi = sinf(thi * 0.5f);
        float chj = cosf(thj * 0.5f), shj = sinf(thj * 0.5f);
        float cpi = cosf(phi_ * 0.5f), spi = sinf(phi_ * 0.5f);
        float cpj = cosf(phj * 0.5f), spj = sinf(phj * 0.5f);
        // u = cos(th/2) e^{+i ph/2},  v = sin(th/2) e^{-i ph/2}
        float uix = chi * cpi, uiy = chi * spi;
        float vix = shi * cpi, viy = -shi * spi;
        float ujx = chj * cpj, ujy = chj * spj;
        float vjx = shj * cpj, vjy = -shj * spj;
        float crx = (uix * vjx - uiy * vjy) - (ujx * vix - ujy * viy);
        float cry = (uix * vjy + uiy * vjx) - (ujx * viy + ujy * vix);
        float chord2 = crx * crx + cry * cry;
        float trunc = 1.f - expf(-100.f * chord2);  // (chord/0.1)^2
        float t2 = trunc * trunc;
        // det = a00*a11 - a01*a10 ; a00=(s0,s1) a01=(s2,s3) a10=(s4,s5) a11=(s6,s7)
        float dr = (s[0] * s[6] - s[1] * s[7]) - (s[2] * s[4] - s[3] * s[5]);
        float di = (s[0] * s[7] + s[1] * s[6]) - (s[2] * s[5] + s[3] * s[4]);
        porb[gp] = make_float2(dr * t2, di * t2);
    }
}

// ---------------- assemble A = pf + cusp, accumulate log_bos ----------------
__global__ __launch_bounds__(256) void assemble_k(
    const float* __restrict__ el, const float2* __restrict__ porb,
    float2* __restrict__ Am, float* acc) {
    __shared__ float sre[256], sim[256];
    int idx = blockIdx.x * 256 + threadIdx.x;
    int i = idx >> 8, j = idx & 255;
    float thi = el[2 * i], phi_ = el[2 * i + 1];
    float thj = el[2 * j], phj = el[2 * j + 1];
    float chi = cosf(thi * 0.5f), shi = sinf(thi * 0.5f);
    float chj = cosf(thj * 0.5f), shj = sinf(thj * 0.5f);
    float cpi = cosf(phi_ * 0.5f), spi = sinf(phi_ * 0.5f);
    float cpj = cosf(phj * 0.5f), spj = sinf(phj * 0.5f);
    float uix = chi * cpi, uiy = chi * spi;
    float vix = shi * cpi, viy = -shi * spi;
    float ujx = chj * cpj, ujy = chj * spj;
    float vjx = shj * cpj, vjy = -shj * spj;
    // elem = u_i v_j - v_i u_j
    float ex = (uix * vjx - uiy * vjy) - (ujx * vix - ujy * viy);
    float ey = (uix * vjy + uiy * vjx) - (ujx * viy + ujy * vix);
    float pfx = 0.f, pfy = 0.f;
    if (i < j) {
        int pp = i * 255 - (i * (i - 1)) / 2 + (j - i - 1);
        float2 t = porb[pp]; pfx = t.x; pfy = t.y;
    } else if (i > j) {
        int pp = j * 255 - (j * (j - 1)) / 2 + (i - j - 1);
        float2 t = porb[pp]; pfx = -t.x; pfy = -t.y;
    }
    float eye = (i == j) ? 1.f : 0.f;
    float ecx = ex + eye, ecy = ey;
    float w = expf(-100.f * (ecx * ecx + ecy * ecy));
    Am[idx] = make_float2(pfx + ecx * w, pfy + ecy * w);
    float lre = 0.f, lim = 0.f;
    if (i != j) {
        float r2 = ex * ex + ey * ey;
        lre = 0.5f * logf(0.01f + r2);
        lim = atan2f(ey, ex);
    }
    sre[threadIdx.x] = lre; sim[threadIdx.x] = lim;
    __syncthreads();
    for (int s2 = 128; s2; s2 >>= 1) {
        if (threadIdx.x < s2) {
            sre[threadIdx.x] += sre[threadIdx.x + s2];
            sim[threadIdx.x] += sim[threadIdx.x + s2];
        }
        __syncthreads();
    }
    if (threadIdx.x == 0) {
        atomicAdd(acc + 0, sre[0]);
        atomicAdd(acc + 1, sim[0]);
    }
}

// ---------------- single-block LU with partial pivoting + finalize ----------------
__global__ __launch_bounds__(1024) void lu_k(
    float2* __restrict__ Am, const float* __restrict__ acc, float* __restrict__ out) {
    __shared__ float red[256];
    __shared__ int redi[256];
    __shared__ float2 Urow[256];
    __shared__ float2 invp_s;
    __shared__ float lsum_s, asum_s;
    __shared__ int nsw_s;
    int t = threadIdx.x;
    if (t == 0) { lsum_s = 0.f; asum_s = 0.f; nsw_s = 0; }
    for (int k = 0; k < NE; ++k) {
        __syncthreads();
        if (t < 256) {
            float val = -1.f; int id = k;
            if (t >= k) {
                float2 a = Am[(size_t)t * NE + k];
                val = fabsf(a.x) + fabsf(a.y);
                id = t;
            }
            red[t] = val; redi[t] = id;
        }
        __syncthreads();
        for (int s2 = 128; s2; s2 >>= 1) {
            if (t < s2 && red[t + s2] > red[t]) {
                red[t] = red[t + s2]; redi[t] = redi[t + s2];
            }
            __syncthreads();
        }
        int piv = redi[0];
        if (piv != k && t < 256) {
            float2 tmp = Am[(size_t)k * NE + t];
            Am[(size_t)k * NE + t] = Am[(size_t)piv * NE + t];
            Am[(size_t)piv * NE + t] = tmp;
        }
        __syncthreads();
        if (t < 256) Urow[t] = Am[(size_t)k * NE + t];
        if (t == 0) {
            float2 d = Am[(size_t)k * NE + k];
            float n2 = d.x * d.x + d.y * d.y;
            lsum_s += 0.5f * logf(n2);
            asum_s += atan2f(d.y, d.x);
            if (piv != k) nsw_s++;
            float inv = 1.f / n2;
            invp_s = make_float2(d.x * inv, -d.y * inv);
        }
        __syncthreads();
        float2 invp = invp_s;
        int w = t >> 6, lane = t & 63;
        for (int i = k + 1 + w; i < NE; i += 16) {
            float2 aik = Am[(size_t)i * NE + k];
            float2 f = make_float2(aik.x * invp.x - aik.y * invp.y,
                                   aik.x * invp.y + aik.y * invp.x);
            for (int j = k + 1 + lane; j < NE; j += 64) {
                float2 u = Urow[j];
                float2 cc = Am[(size_t)i * NE + j];
                cc.x -= f.x * u.x - f.y * u.y;
                cc.y -= f.x * u.y + f.y * u.x;
                Am[(size_t)i * NE + j] = cc;
            }
        }
    }
    __syncthreads();
    if (t == 0) {
        float ang = asum_s + 3.14159265358979323846f * (float)nsw_s;
        ang = ang - 6.283185307179586f * rintf(ang * 0.15915494309189535f);
        out[0] = 0.5f * lsum_s + acc[0];
        out[1] = 0.5f * ang + acc[1];
    }
}

// ---------------- host launch ----------------
extern "C" void kernel_launch(void* const* d_in, const int* in_sizes, int n_in,
                              void* d_out, int out_size, void* d_ws, size_t ws_size,
                              hipStream_t stream) {
    (void)in_sizes; (void)n_in; (void)out_size;
    const float* el   = (const float*)d_in[0];
    const float* Win  = (const float*)d_in[1];
    const float* Wq   = (const float*)d_in[2];
    const float* bq   = (const float*)d_in[3];
    const float* Wk   = (const float*)d_in[4];
    const float* bk   = (const float*)d_in[5];
    const float* Wv   = (const float*)d_in[6];
    const float* bv   = (const float*)d_in[7];
    const float* Wo   = (const float*)d_in[8];
    const float* bo   = (const float*)d_in[9];
    const float* W1   = (const float*)d_in[10];
    const float* ln1s = (const float*)d_in[11];
    const float* ln1b = (const float*)d_in[12];
    const float* W2   = (const float*)d_in[13];
    const float* b2   = (const float*)d_in[14];
    const float* ln2s = (const float*)d_in[15];
    const float* ln2b = (const float*)d_in[16];
    const float* Wor  = (const float*)d_in[17];
    const float* Woi  = (const float*)d_in[18];

    char* wp = (char*)d_ws;
    auto alloc = [&](size_t b) {
        char* r = wp;
        wp += (b + 255) & ~(size_t)255;
        return r;
    };
    int*    ipb  = (int*)alloc((size_t)P_TOT * 4);
    int*    jpb  = (int*)alloc((size_t)P_TOT * 4);
    float2* porb = (float2*)alloc((size_t)P_TOT * 8);
    float2* Am   = (float2*)alloc((size_t)NE * NE * 8);
    float*  acc  = (float*)alloc(256);
    float*  hb   = (float*)alloc((size_t)MC * DD * 4);
    float*  qb   = (float*)alloc((size_t)MC * DD * 4);
    float*  kb   = (float*)alloc((size_t)MC * DD * 4);
    float*  vb   = (float*)alloc((size_t)MC * DD * 4);
    size_t need = (size_t)(wp - (char*)d_ws);
    if (need > ws_size) {
        // fail loud but safely: write zeros
        zero_k<<<1, 64, 0, stream>>>((float*)d_out);
        return;
    }

    idx_k<<<1, 256, 0, stream>>>(ipb, jpb);
    zero_k<<<1, 64, 0, stream>>>(acc);

    dim3 ggrid(MC / 64, 4);
    for (int c = 0; c < NCHUNK; ++c) {
        int P0 = c * PC;
        embed_k<<<MC, 256, 0, stream>>>(el, Win, ipb, jpb, hb, P0);
        for (int l = 0; l < NL; ++l) {
            size_t woff = (size_t)l * 65536, boff = (size_t)l * 256;
            gemm_k<true, false><<<ggrid, 256, 0, stream>>>(hb, Wq + woff, bq + boff, nullptr, qb);
            gemm_k<true, false><<<ggrid, 256, 0, stream>>>(hb, Wk + woff, bk + boff, nullptr, kb);
            gemm_k<true, false><<<ggrid, 256, 0, stream>>>(hb, Wv + woff, bv + boff, nullptr, vb);
            attn_k<<<PC, 256, 0, stream>>>(qb, kb, vb);  // o -> qb
            gemm_k<true, false><<<ggrid, 256, 0, stream>>>(qb, Wo + woff, bo + boff, nullptr, kb); // mha -> kb
            gemm_k<false, true><<<ggrid, 256, 0, stream>>>(kb, W1 + woff, nullptr, hb, vb);        // h+mha@W1 -> vb
            ln_a_k<<<MC / 4, 256, 0, stream>>>(vb, hb, ln1s + boff, ln1b + boff);                  // LN1 -> hb
            gemm_k<true, false><<<ggrid, 256, 0, stream>>>(hb, W2 + woff, b2 + boff, nullptr, qb); // t2 -> qb
            ln_b_k<<<MC / 4, 256, 0, stream>>>(hb, qb, ln2s + boff, ln2b + boff);                  // LN2 in place
        }
        orb_k<<<PC / 4, 256, 0, stream>>>(hb, Wor, Woi, el, ipb, jpb, porb, P0);
    }
    assemble_k<<<NE, 256, 0, stream>>>(el, porb, Am, acc);
    lu_k<<<1, 1024, 0, stream>>>(Am, acc, (float*)d_out);
}

// Round 2
// 2865.737 us; speedup vs baseline: 1.5696x; 1.5696x over previous
//
#include <hip/hip_runtime.h>
#include <math.h>

#define NE 256
#define DD 256
#define NH 4
#define DH 64
#define NL 2
#define P_TOT 32640          // NE*(NE-1)/2
#define NCHUNK 4
#define PC (P_TOT / NCHUNK)  // 8160 pairs per chunk
#define MC (2 * PC)          // 16320 rows per chunk (divisible by 64)
#define NB 32                // LU panel width
#define NPANEL (NE / NB)

// ---------------- small helpers ----------------
__global__ void idx_k(int* __restrict__ ip, int* __restrict__ jp) {
    int i = threadIdx.x;  // 0..255
    int base = i * 255 - (i * (i - 1)) / 2;
    for (int j = i + 1; j < NE; ++j) {
        ip[base + j - i - 1] = i;
        jp[base + j - i - 1] = j;
    }
}

__global__ void zero_k(float* __restrict__ acc) {
    if (threadIdx.x < 8) acc[threadIdx.x] = 0.f;
}

// ---------------- input embedding: h = feat @ W_in ----------------
__global__ __launch_bounds__(256) void embed_k(
    const float* __restrict__ el, const float* __restrict__ Win,
    const int* __restrict__ ip, const int* __restrict__ jp,
    float* __restrict__ h, int P0) {
    int r = blockIdx.x;        // local row, 0..MC-1
    int n = threadIdx.x;       // 0..255
    int gp = P0 + (r >> 1);
    int e = (r & 1) ? jp[gp] : ip[gp];
    float th = el[2 * e], ph = el[2 * e + 1];
    float st = sinf(th);
    float f0 = cosf(th), f1 = st * cosf(ph), f2 = st * sinf(ph);
    h[(size_t)r * DD + n] = f0 * Win[n] + f1 * Win[DD + n] + f2 * Win[2 * DD + n];
}

// ---------------- fp32 tiled GEMM: C = A@B (+bias) (+residual) ----------------
template <bool BIAS, bool RES>
__global__ __launch_bounds__(256) void gemm_k(
    const float* __restrict__ A, const float* __restrict__ B,
    const float* __restrict__ bias, const float* __restrict__ Rm,
    float* __restrict__ C) {
    __shared__ float As[16][68];
    __shared__ float Bs[16][68];
    int t = threadIdx.x;
    int tm = t >> 4, tn = t & 15;
    int row0 = blockIdx.x * 64, col0 = blockIdx.y * 64;
    float acc[4][4] = {};
    for (int kt = 0; kt < 16; ++kt) {
        int k0 = kt * 16;
        {
            int r = t >> 2, kk = (t & 3) * 4;
            const float4 av = *(const float4*)(A + (size_t)(row0 + r) * DD + k0 + kk);
            As[kk + 0][r] = av.x; As[kk + 1][r] = av.y;
            As[kk + 2][r] = av.z; As[kk + 3][r] = av.w;
        }
        {
            int n = t & 63, kb = t >> 6;
#pragma unroll
            for (int u = 0; u < 4; ++u)
                Bs[kb + 4 * u][n] = B[(size_t)(k0 + kb + 4 * u) * DD + col0 + n];
        }
        __syncthreads();
#pragma unroll
        for (int kk = 0; kk < 16; ++kk) {
            float av0 = As[kk][tm * 4 + 0], av1 = As[kk][tm * 4 + 1];
            float av2 = As[kk][tm * 4 + 2], av3 = As[kk][tm * 4 + 3];
            float bv0 = Bs[kk][tn * 4 + 0], bv1 = Bs[kk][tn * 4 + 1];
            float bv2 = Bs[kk][tn * 4 + 2], bv3 = Bs[kk][tn * 4 + 3];
            acc[0][0] += av0 * bv0; acc[0][1] += av0 * bv1; acc[0][2] += av0 * bv2; acc[0][3] += av0 * bv3;
            acc[1][0] += av1 * bv0; acc[1][1] += av1 * bv1; acc[1][2] += av1 * bv2; acc[1][3] += av1 * bv3;
            acc[2][0] += av2 * bv0; acc[2][1] += av2 * bv1; acc[2][2] += av2 * bv2; acc[2][3] += av2 * bv3;
            acc[3][0] += av3 * bv0; acc[3][1] += av3 * bv1; acc[3][2] += av3 * bv2; acc[3][3] += av3 * bv3;
        }
        __syncthreads();
    }
#pragma unroll
    for (int i2 = 0; i2 < 4; ++i2) {
        int row = row0 + tm * 4 + i2;
#pragma unroll
        for (int j2 = 0; j2 < 4; ++j2) {
            int col = col0 + tn * 4 + j2;
            float v = acc[i2][j2];
            if (BIAS) v += bias[col];
            if (RES) v += Rm[(size_t)row * DD + col];
            C[(size_t)row * DD + col] = v;
        }
    }
}

// ---------------- attention (seq=2), one wave per (pair, head) ----------------
__global__ __launch_bounds__(256) void attn_k(
    float* qo, const float* __restrict__ km, const float* __restrict__ vm) {
    int wid = threadIdx.x >> 6, lane = threadIdx.x & 63;
    int gw = blockIdx.x * 4 + wid;
    int p = gw >> 2, hh = gw & 3;
    size_t r0 = (size_t)(2 * p) * DD + hh * DH + lane;
    size_t r1 = r0 + DD;
    float q0 = qo[r0] * 0.125f, q1 = qo[r1] * 0.125f;
    float k0 = km[r0], k1 = km[r1];
    float v0 = vm[r0], v1 = vm[r1];
    float s00 = q0 * k0, s01 = q0 * k1, s10 = q1 * k0, s11 = q1 * k1;
#pragma unroll
    for (int off = 32; off; off >>= 1) {
        s00 += __shfl_xor(s00, off, 64);
        s01 += __shfl_xor(s01, off, 64);
        s10 += __shfl_xor(s10, off, 64);
        s11 += __shfl_xor(s11, off, 64);
    }
    float m0 = fmaxf(s00, s01), m1 = fmaxf(s10, s11);
    float e00 = expf(s00 - m0), e01 = expf(s01 - m0);
    float e10 = expf(s10 - m1), e11 = expf(s11 - m1);
    float i0 = 1.f / (e00 + e01), i1 = 1.f / (e10 + e11);
    float o0 = (e00 * i0) * v0 + (e01 * i0) * v1;
    float o1 = (e10 * i1) * v0 + (e11 * i1) * v1;
    qo[r0] = o0;
    qo[r1] = o1;
}

// ---------------- layernorm variants (wave per row) ----------------
__global__ __launch_bounds__(256) void ln_a_k(
    const float* __restrict__ X, float* __restrict__ Hm,
    const float* __restrict__ sc, const float* __restrict__ bi) {
    int wid = threadIdx.x >> 6, lane = threadIdx.x & 63;
    int r = blockIdx.x * 4 + wid;
    float x[4]; float sum = 0.f, sq = 0.f;
#pragma unroll
    for (int u = 0; u < 4; ++u) {
        x[u] = X[(size_t)r * DD + u * 64 + lane];
        sum += x[u]; sq += x[u] * x[u];
    }
#pragma unroll
    for (int off = 32; off; off >>= 1) {
        sum += __shfl_xor(sum, off, 64);
        sq += __shfl_xor(sq, off, 64);
    }
    float m = sum * (1.f / 256.f);
    float var = sq * (1.f / 256.f) - m * m;
    float rs = rsqrtf(var + 1e-5f);
#pragma unroll
    for (int u = 0; u < 4; ++u) {
        int d = u * 64 + lane;
        Hm[(size_t)r * DD + d] = (x[u] - m) * rs * sc[d] + bi[d];
    }
}

// h = LN(h + tanh(T)) in place
__global__ __launch_bounds__(256) void ln_b_k(
    float* Hm, const float* __restrict__ T,
    const float* __restrict__ sc, const float* __restrict__ bi) {
    int wid = threadIdx.x >> 6, lane = threadIdx.x & 63;
    int r = blockIdx.x * 4 + wid;
    float x[4]; float sum = 0.f, sq = 0.f;
#pragma unroll
    for (int u = 0; u < 4; ++u) {
        size_t idx = (size_t)r * DD + u * 64 + lane;
        x[u] = Hm[idx] + tanhf(T[idx]);
        sum += x[u]; sq += x[u] * x[u];
    }
#pragma unroll
    for (int off = 32; off; off >>= 1) {
        sum += __shfl_xor(sum, off, 64);
        sq += __shfl_xor(sq, off, 64);
    }
    float m = sum * (1.f / 256.f);
    float var = sq * (1.f / 256.f) - m * m;
    float rs = rsqrtf(var + 1e-5f);
#pragma unroll
    for (int u = 0; u < 4; ++u) {
        int d = u * 64 + lane;
        Hm[(size_t)r * DD + d] = (x[u] - m) * rs * sc[d] + bi[d];
    }
}

// ---------------- per-pair orbitals + 2x2 det ----------------
__global__ __launch_bounds__(256) void orb_k(
    const float* __restrict__ h, const float* __restrict__ Wr, const float* __restrict__ Wi,
    const float* __restrict__ el, const int* __restrict__ ip, const int* __restrict__ jp,
    float2* __restrict__ porb, int P0) {
    int wid = threadIdx.x >> 6, lane = threadIdx.x & 63;
    int p = blockIdx.x * 4 + wid;
    const float* h0 = h + (size_t)(2 * p) * DD;
    float s[8] = {0, 0, 0, 0, 0, 0, 0, 0};
#pragma unroll
    for (int u = 0; u < 4; ++u) {
        int d = u * 64 + lane;
        float x0 = h0[d], x1 = h0[DD + d];
        float wr0 = Wr[2 * d], wr1 = Wr[2 * d + 1];
        float wi0 = Wi[2 * d], wi1 = Wi[2 * d + 1];
        s[0] += x0 * wr0; s[1] += x0 * wi0; s[2] += x0 * wr1; s[3] += x0 * wi1;
        s[4] += x1 * wr0; s[5] += x1 * wi0; s[6] += x1 * wr1; s[7] += x1 * wi1;
    }
#pragma unroll
    for (int off = 32; off; off >>= 1) {
#pragma unroll
        for (int q2 = 0; q2 < 8; ++q2) s[q2] += __shfl_xor(s[q2], off, 64);
    }
    if (lane == 0) {
        int gp = P0 + p;
        int i = ip[gp], j = jp[gp];
        float thi = el[2 * i], phi_ = el[2 * i + 1];
        float thj = el[2 * j], phj = el[2 * j + 1];
        float chi = cosf(thi * 0.5f), shi = sinf(thi * 0.5f);
        float chj = cosf(thj * 0.5f), shj = sinf(thj * 0.5f);
        float cpi = cosf(phi_ * 0.5f), spi = sinf(phi_ * 0.5f);
        float cpj = cosf(phj * 0.5f), spj = sinf(phj * 0.5f);
        float uix = chi * cpi, uiy = chi * spi;
        float vix = shi * cpi, viy = -shi * spi;
        float ujx = chj * cpj, ujy = chj * spj;
        float vjx = shj * cpj, vjy = -shj * spj;
        float crx = (uix * vjx - uiy * vjy) - (ujx * vix - ujy * viy);
        float cry = (uix * vjy + uiy * vjx) - (ujx * viy + ujy * vix);
        float chord2 = crx * crx + cry * cry;
        float trunc = 1.f - expf(-100.f * chord2);
        float t2 = trunc * trunc;
        float dr = (s[0] * s[6] - s[1] * s[7]) - (s[2] * s[4] - s[3] * s[5]);
        float di = (s[0] * s[7] + s[1] * s[6]) - (s[2] * s[5] + s[3] * s[4]);
        porb[gp] = make_float2(dr * t2, di * t2);
    }
}

// ---------------- assemble A = pf + cusp, accumulate log_bos ----------------
__global__ __launch_bounds__(256) void assemble_k(
    const float* __restrict__ el, const float2* __restrict__ porb,
    float2* __restrict__ Am, float* acc) {
    __shared__ float sre[256], sim[256];
    int idx = blockIdx.x * 256 + threadIdx.x;
    int i = idx >> 8, j = idx & 255;
    float thi = el[2 * i], phi_ = el[2 * i + 1];
    float thj = el[2 * j], phj = el[2 * j + 1];
    float chi = cosf(thi * 0.5f), shi = sinf(thi * 0.5f);
    float chj = cosf(thj * 0.5f), shj = sinf(thj * 0.5f);
    float cpi = cosf(phi_ * 0.5f), spi = sinf(phi_ * 0.5f);
    float cpj = cosf(phj * 0.5f), spj = sinf(phj * 0.5f);
    float uix = chi * cpi, uiy = chi * spi;
    float vix = shi * cpi, viy = -shi * spi;
    float ujx = chj * cpj, ujy = chj * spj;
    float vjx = shj * cpj, vjy = -shj * spj;
    float ex = (uix * vjx - uiy * vjy) - (ujx * vix - ujy * viy);
    float ey = (uix * vjy + uiy * vjx) - (ujx * viy + ujy * vix);
    float pfx = 0.f, pfy = 0.f;
    if (i < j) {
        int pp = i * 255 - (i * (i - 1)) / 2 + (j - i - 1);
        float2 t = porb[pp]; pfx = t.x; pfy = t.y;
    } else if (i > j) {
        int pp = j * 255 - (j * (j - 1)) / 2 + (i - j - 1);
        float2 t = porb[pp]; pfx = -t.x; pfy = -t.y;
    }
    float eye = (i == j) ? 1.f : 0.f;
    float ecx = ex + eye, ecy = ey;
    float w = expf(-100.f * (ecx * ecx + ecy * ecy));
    Am[idx] = make_float2(pfx + ecx * w, pfy + ecy * w);
    float lre = 0.f, lim = 0.f;
    if (i != j) {
        float r2 = ex * ex + ey * ey;
        lre = 0.5f * logf(0.01f + r2);
        lim = atan2f(ey, ex);
    }
    sre[threadIdx.x] = lre; sim[threadIdx.x] = lim;
    __syncthreads();
    for (int s2 = 128; s2; s2 >>= 1) {
        if (threadIdx.x < s2) {
            sre[threadIdx.x] += sre[threadIdx.x + s2];
            sim[threadIdx.x] += sim[threadIdx.x + s2];
        }
        __syncthreads();
    }
    if (threadIdx.x == 0) {
        atomicAdd(acc + 0, sre[0]);
        atomicAdd(acc + 1, sim[0]);
    }
}

// ---------------- blocked LU: panel factorization (LDS-resident) ----------------
// Factors A[k0:256, k0:k0+NB] with partial pivoting. Panel lives in LDS.
// Records global pivot rows in pivg[0..NB), accumulates diag logs into acc[2..4].
__global__ __launch_bounds__(1024) void panel_k(
    float2* __restrict__ Am, int* __restrict__ pivg, float* __restrict__ acc, int k0) {
    __shared__ float2 Pn[256][NB + 1];   // 67.6 KB of the 160 KB group segment
    __shared__ float rmax[16];
    __shared__ int rmaxi[16];
    __shared__ int piv_s;
    __shared__ float2 inv_s;
    __shared__ float lsum_s, asum_s;
    __shared__ int nsw_s;
    int t = threadIdx.x;
    int lane = t & 63, w = t >> 6;
    int nr = 256 - k0;
    for (int idx = t; idx < nr * NB; idx += 1024) {
        int lr = idx >> 5, c = idx & 31;
        Pn[lr][c] = Am[(size_t)(k0 + lr) * NE + k0 + c];
    }
    if (t == 0) { lsum_s = 0.f; asum_s = 0.f; nsw_s = 0; }
    __syncthreads();
    for (int j = 0; j < NB; ++j) {
        // pivot search over column j, local rows j..nr-1 (|re|+|im|, LAPACK cabs1)
        float val = -1.f; int id = j;
        if (t >= j && t < nr) {
            float2 a = Pn[t][j];
            val = fabsf(a.x) + fabsf(a.y);
            id = t;
        }
#pragma unroll
        for (int off = 32; off; off >>= 1) {
            float ov = __shfl_xor(val, off, 64);
            int oi = __shfl_xor(id, off, 64);
            if (ov > val) { val = ov; id = oi; }
        }
        if (lane == 0) { rmax[w] = val; rmaxi[w] = id; }
        __syncthreads();
        if (t == 0) {
            float bv = rmax[0]; int bi = rmaxi[0];
            for (int q = 1; q < 16; ++q)
                if (rmax[q] > bv) { bv = rmax[q]; bi = rmaxi[q]; }
            piv_s = bi;
            pivg[j] = k0 + bi;
        }
        __syncthreads();
        int piv = piv_s;
        if (piv != j && t < NB) {
            float2 tmp = Pn[j][t]; Pn[j][t] = Pn[piv][t]; Pn[piv][t] = tmp;
        }
        __syncthreads();
        if (t == 0) {
            float2 d = Pn[j][j];
            float n2 = d.x * d.x + d.y * d.y;
            lsum_s += 0.5f * logf(n2);
            asum_s += atan2f(d.y, d.x);
            if (piv != j) nsw_s++;
            float iv = 1.f / n2;
            inv_s = make_float2(d.x * iv, -d.y * iv);
        }
        __syncthreads();
        float2 ip = inv_s;
        for (int r = j + 1 + t; r < nr; r += 1024) {
            float2 a = Pn[r][j];
            Pn[r][j] = make_float2(a.x * ip.x - a.y * ip.y, a.x * ip.y + a.y * ip.x);
        }
        __syncthreads();
        int c = t & 31, rb = t >> 5;
        if (c > j) {
            float2 u = Pn[j][c];
            for (int r = j + 1 + rb; r < nr; r += 32) {
                float2 l = Pn[r][j];
                float2 a = Pn[r][c];
                a.x -= l.x * u.x - l.y * u.y;
                a.y -= l.x * u.y + l.y * u.x;
                Pn[r][c] = a;
            }
        }
        __syncthreads();
    }
    for (int idx = t; idx < nr * NB; idx += 1024) {
        int lr = idx >> 5, c = idx & 31;
        Am[(size_t)(k0 + lr) * NE + k0 + c] = Pn[lr][c];
    }
    if (t == 0) {
        acc[2] += lsum_s;
        acc[3] += asum_s;
        acc[4] += (float)nsw_s;
    }
}

// apply panel pivots to off-panel columns (laswp). Thread per column, ordered in j.
__global__ __launch_bounds__(256) void swap_k(
    float2* __restrict__ Am, const int* __restrict__ pivg, int k0) {
    __shared__ int pv[NB];
    int t = threadIdx.x;
    if (t < NB) pv[t] = pivg[t];
    __syncthreads();
    int c = t;
    if (c >= k0 && c < k0 + NB) return;
    for (int j = 0; j < NB; ++j) {
        int r1 = k0 + j, r2 = pv[j];
        if (r1 != r2) {
            float2 a = Am[(size_t)r1 * NE + c];
            float2 b = Am[(size_t)r2 * NE + c];
            Am[(size_t)r1 * NE + c] = b;
            Am[(size_t)r2 * NE + c] = a;
        }
    }
}

// U12 = L11^{-1} A12 (unit lower). Thread per column; L11 in LDS; x[] unrolled regs.
__global__ __launch_bounds__(256) void trsm_k(float2* __restrict__ Am, int k0) {
    __shared__ float2 Ls[NB][NB + 1];
    int t = threadIdx.x;
    for (int idx = t; idx < NB * NB; idx += 256) {
        int lr = idx >> 5, lc = idx & 31;
        Ls[lr][lc] = Am[(size_t)(k0 + lr) * NE + k0 + lc];
    }
    __syncthreads();
    int ncols = NE - k0 - NB;
    if (t >= ncols) return;
    int col = k0 + NB + t;
    float2 x[NB];
#pragma unroll
    for (int i = 0; i < NB; ++i) x[i] = Am[(size_t)(k0 + i) * NE + col];
#pragma unroll
    for (int i = 1; i < NB; ++i) {
        float2 xi = x[i];
#pragma unroll
        for (int j = 0; j < i; ++j) {
            float2 l = Ls[i][j];
            xi.x -= l.x * x[j].x - l.y * x[j].y;
            xi.y -= l.x * x[j].y + l.y * x[j].x;
        }
        x[i] = xi;
    }
#pragma unroll
    for (int i = 1; i < NB; ++i) Am[(size_t)(k0 + i) * NE + col] = x[i];
}

// A22 -= L21 @ U12, complex, K=NB. 32x32 tile per block.
__global__ __launch_bounds__(256) void update_k(float2* __restrict__ Am, int k0) {
    __shared__ float2 Lt[NB][NB + 1];
    __shared__ float2 Ut[NB][NB + 1];
    int t = threadIdx.x;
    int r0 = k0 + NB + blockIdx.x * NB;
    int c0 = k0 + NB + blockIdx.y * NB;
    for (int idx = t; idx < NB * NB; idx += 256) {
        int a = idx >> 5, b = idx & 31;
        Lt[a][b] = Am[(size_t)(r0 + a) * NE + k0 + b];
        Ut[a][b] = Am[(size_t)(k0 + a) * NE + c0 + b];
    }
    __syncthreads();
    int lr = t >> 3, lc0 = (t & 7) * 4;
    float2 s0 = {0.f, 0.f}, s1 = {0.f, 0.f}, s2 = {0.f, 0.f}, s3 = {0.f, 0.f};
#pragma unroll
    for (int k = 0; k < NB; ++k) {
        float2 a = Lt[lr][k];
        float2 u0 = Ut[k][lc0 + 0], u1 = Ut[k][lc0 + 1];
        float2 u2 = Ut[k][lc0 + 2], u3 = Ut[k][lc0 + 3];
        s0.x += a.x * u0.x - a.y * u0.y; s0.y += a.x * u0.y + a.y * u0.x;
        s1.x += a.x * u1.x - a.y * u1.y; s1.y += a.x * u1.y + a.y * u1.x;
        s2.x += a.x * u2.x - a.y * u2.y; s2.y += a.x * u2.y + a.y * u2.x;
        s3.x += a.x * u3.x - a.y * u3.y; s3.y += a.x * u3.y + a.y * u3.x;
    }
    size_t base = (size_t)(r0 + lr) * NE + c0 + lc0;
    float2 cc;
    cc = Am[base + 0]; cc.x -= s0.x; cc.y -= s0.y; Am[base + 0] = cc;
    cc = Am[base + 1]; cc.x -= s1.x; cc.y -= s1.y; Am[base + 1] = cc;
    cc = Am[base + 2]; cc.x -= s2.x; cc.y -= s2.y; Am[base + 2] = cc;
    cc = Am[base + 3]; cc.x -= s3.x; cc.y -= s3.y; Am[base + 3] = cc;
}

__global__ void finalize_k(const float* __restrict__ acc, float* __restrict__ out) {
    if (threadIdx.x == 0) {
        float ang = acc[3] + 3.14159265358979323846f * acc[4];
        ang -= 6.283185307179586f * rintf(ang * 0.15915494309189535f);
        out[0] = 0.5f * acc[2] + acc[0];
        out[1] = 0.5f * ang + acc[1];
    }
}

// ---------------- host launch ----------------
extern "C" void kernel_launch(void* const* d_in, const int* in_sizes, int n_in,
                              void* d_out, int out_size, void* d_ws, size_t ws_size,
                              hipStream_t stream) {
    (void)in_sizes; (void)n_in; (void)out_size;
    const float* el   = (const float*)d_in[0];
    const float* Win  = (const float*)d_in[1];
    const float* Wq   = (const float*)d_in[2];
    const float* bq   = (const float*)d_in[3];
    const float* Wk   = (const float*)d_in[4];
    const float* bk   = (const float*)d_in[5];
    const float* Wv   = (const float*)d_in[6];
    const float* bv   = (const float*)d_in[7];
    const float* Wo   = (const float*)d_in[8];
    const float* bo   = (const float*)d_in[9];
    const float* W1   = (const float*)d_in[10];
    const float* ln1s = (const float*)d_in[11];
    const float* ln1b = (const float*)d_in[12];
    const float* W2   = (const float*)d_in[13];
    const float* b2   = (const float*)d_in[14];
    const float* ln2s = (const float*)d_in[15];
    const float* ln2b = (const float*)d_in[16];
    const float* Wor  = (const float*)d_in[17];
    const float* Woi  = (const float*)d_in[18];

    char* wp = (char*)d_ws;
    auto alloc = [&](size_t b) {
        char* r = wp;
        wp += (b + 255) & ~(size_t)255;
        return r;
    };
    int*    ipb  = (int*)alloc((size_t)P_TOT * 4);
    int*    jpb  = (int*)alloc((size_t)P_TOT * 4);
    float2* porb = (float2*)alloc((size_t)P_TOT * 8);
    float2* Am   = (float2*)alloc((size_t)NE * NE * 8);
    float*  acc  = (float*)alloc(256);
    int*    pivg = (int*)alloc((size_t)NE * 4);
    float*  hb   = (float*)alloc((size_t)MC * DD * 4);
    float*  qb   = (float*)alloc((size_t)MC * DD * 4);
    float*  kb   = (float*)alloc((size_t)MC * DD * 4);
    float*  vb   = (float*)alloc((size_t)MC * DD * 4);
    size_t need = (size_t)(wp - (char*)d_ws);
    if (need > ws_size) {
        zero_k<<<1, 64, 0, stream>>>((float*)d_out);
        return;
    }

    idx_k<<<1, 256, 0, stream>>>(ipb, jpb);
    zero_k<<<1, 64, 0, stream>>>(acc);

    dim3 ggrid(MC / 64, 4);
    for (int c = 0; c < NCHUNK; ++c) {
        int P0 = c * PC;
        embed_k<<<MC, 256, 0, stream>>>(el, Win, ipb, jpb, hb, P0);
        for (int l = 0; l < NL; ++l) {
            size_t woff = (size_t)l * 65536, boff = (size_t)l * 256;
            gemm_k<true, false><<<ggrid, 256, 0, stream>>>(hb, Wq + woff, bq + boff, nullptr, qb);
            gemm_k<true, false><<<ggrid, 256, 0, stream>>>(hb, Wk + woff, bk + boff, nullptr, kb);
            gemm_k<true, false><<<ggrid, 256, 0, stream>>>(hb, Wv + woff, bv + boff, nullptr, vb);
            attn_k<<<PC, 256, 0, stream>>>(qb, kb, vb);
            gemm_k<true, false><<<ggrid, 256, 0, stream>>>(qb, Wo + woff, bo + boff, nullptr, kb);
            gemm_k<false, true><<<ggrid, 256, 0, stream>>>(kb, W1 + woff, nullptr, hb, vb);
            ln_a_k<<<MC / 4, 256, 0, stream>>>(vb, hb, ln1s + boff, ln1b + boff);
            gemm_k<true, false><<<ggrid, 256, 0, stream>>>(hb, W2 + woff, b2 + boff, nullptr, qb);
            ln_b_k<<<MC / 4, 256, 0, stream>>>(hb, qb, ln2s + boff, ln2b + boff);
        }
        orb_k<<<PC / 4, 256, 0, stream>>>(hb, Wor, Woi, el, ipb, jpb, porb, P0);
    }
    assemble_k<<<NE, 256, 0, stream>>>(el, porb, Am, acc);

    for (int p = 0; p < NPANEL; ++p) {
        int k0 = p * NB;
        panel_k<<<1, 1024, 0, stream>>>(Am, pivg + p * NB, acc, k0);
        swap_k<<<1, 256, 0, stream>>>(Am, pivg + p * NB, k0);
        int m = NE - k0 - NB;
        if (m > 0) {
            trsm_k<<<1, 256, 0, stream>>>(Am, k0);
            dim3 ug(m / NB, m / NB);
            update_k<<<ug, 256, 0, stream>>>(Am, k0);
        }
    }
    finalize_k<<<1, 64, 0, stream>>>(acc, (float*)d_out);
}

// Round 3
// 1381.022 us; speedup vs baseline: 3.2570x; 2.0751x over previous
//
// R3: bf16 MFMA GEMMs (128x128 tile, BK=64, global_load_lds + XOR-swizzled LDS),
//     bf16 activations, fused QKV (N=768), panel_k 512t/3-barrier, swap fused into trsm.
#include <hip/hip_runtime.h>
#include <math.h>
#include <stdint.h>

#define NE 256
#define DD 256
#define NL 2
#define P_TOT 32640          // NE*(NE-1)/2
#define NCHUNK 3
#define PC (P_TOT / NCHUNK)  // 10880 pairs per chunk
#define MC (2 * PC)          // 21760 rows = 170*128
#define MT (MC / 128)        // 170
#define NB 32                // LU panel width
#define NPANEL (NE / NB)

typedef __bf16 bf16x8 __attribute__((ext_vector_type(8)));
typedef float f32x4 __attribute__((ext_vector_type(4)));

__device__ __forceinline__ float bf2f(ushort h) {
    union { unsigned u; float f; } c; c.u = ((unsigned)h) << 16; return c.f;
}
__device__ __forceinline__ ushort f2bf(float f) {
    union { float f; unsigned u; } c; c.f = f;
    unsigned u = c.u;
    return (ushort)((u + 0x7fffu + ((u >> 16) & 1u)) >> 16);
}

#define GLD16(gp, lp) __builtin_amdgcn_global_load_lds( \
    (const __attribute__((address_space(1))) unsigned int*)(uintptr_t)(gp), \
    (__attribute__((address_space(3))) unsigned int*)(uintptr_t)(lp), 16, 0, 0)

// ---------------- small helpers ----------------
__global__ void idx_k(int* __restrict__ ip, int* __restrict__ jp) {
    int i = threadIdx.x;  // 0..255
    int base = i * 255 - (i * (i - 1)) / 2;
    for (int j = i + 1; j < NE; ++j) {
        ip[base + j - i - 1] = i;
        jp[base + j - i - 1] = j;
    }
}

__global__ void zero_k(float* __restrict__ acc) {
    if (threadIdx.x < 8) acc[threadIdx.x] = 0.f;
}

// ---------------- weight prep: Bt[n][k] = W[k][n] in bf16 ----------------
__global__ __launch_bounds__(256) void prep_w_k(
    const float* __restrict__ Wq, const float* __restrict__ Wk, const float* __restrict__ Wv,
    const float* __restrict__ Wo, const float* __restrict__ W1, const float* __restrict__ W2,
    ushort* __restrict__ Wqkv_t, ushort* __restrict__ Woth_t) {
    __shared__ float Ts[32][33];
    int z = blockIdx.z, l = z / 6, m = z % 6;
    const float* src;
    ushort* dst;
    if (m == 0)      { src = Wq + l * 65536; dst = Wqkv_t + (size_t)l * 768 * 256 + 0 * 65536; }
    else if (m == 1) { src = Wk + l * 65536; dst = Wqkv_t + (size_t)l * 768 * 256 + 1 * 65536; }
    else if (m == 2) { src = Wv + l * 65536; dst = Wqkv_t + (size_t)l * 768 * 256 + 2 * 65536; }
    else             { src = (m == 3 ? Wo : m == 4 ? W1 : W2) + l * 65536;
                       dst = Woth_t + (size_t)(l * 3 + (m - 3)) * 65536; }
    int k0 = blockIdx.x * 32, n0 = blockIdx.y * 32;
    int t = threadIdx.x, tr = t >> 5, tc = t & 31;
    for (int i = tr; i < 32; i += 8) Ts[i][tc] = src[(size_t)(k0 + i) * 256 + n0 + tc];
    __syncthreads();
    for (int i = tr; i < 32; i += 8) dst[(size_t)(n0 + i) * 256 + k0 + tc] = f2bf(Ts[tc][i]);
}

__global__ void prep_b_k(const float* __restrict__ bq, const float* __restrict__ bk,
                         const float* __restrict__ bv, float* __restrict__ bqkv) {
    int l = blockIdx.x, t = threadIdx.x;
    bqkv[l * 768 + t] = bq[l * 256 + t];
    bqkv[l * 768 + 256 + t] = bk[l * 256 + t];
    bqkv[l * 768 + 512 + t] = bv[l * 256 + t];
}

// ---------------- embedding: h = feat @ W_in (bf16 out) ----------------
__global__ __launch_bounds__(256) void embed_k(
    const float* __restrict__ el, const float* __restrict__ Win,
    const int* __restrict__ ip, const int* __restrict__ jp,
    ushort* __restrict__ h, int P0) {
    int w = threadIdx.x >> 6, lane = threadIdx.x & 63;
    int r = blockIdx.x * 4 + w;
    int gp = P0 + (r >> 1);
    int e = (r & 1) ? jp[gp] : ip[gp];
    float th = el[2 * e], ph = el[2 * e + 1];
    float st = sinf(th);
    float f0 = cosf(th), f1 = st * cosf(ph), f2 = st * sinf(ph);
    int n = lane * 4;
    float4 w0 = *(const float4*)&Win[n];
    float4 w1 = *(const float4*)&Win[256 + n];
    float4 w2 = *(const float4*)&Win[512 + n];
    ushort4 o;
    o.x = f2bf(f0 * w0.x + f1 * w1.x + f2 * w2.x);
    o.y = f2bf(f0 * w0.y + f1 * w1.y + f2 * w2.y);
    o.z = f2bf(f0 * w0.z + f1 * w1.z + f2 * w2.z);
    o.w = f2bf(f0 * w0.w + f1 * w1.w + f2 * w2.w);
    *(ushort4*)&h[(size_t)r * 256 + n] = o;
}

// ---------------- bf16 MFMA GEMM: C = A@B (+bias) (+residual) ----------------
// A:[M,lda] bf16 row-major; Bt:[N,256] bf16 (B transposed); C:[M,ldc] bf16.
// K=256 fixed. grid (M/128, N/128), 256 threads.
template <bool BIAS, bool RES>
__global__ __launch_bounds__(256) void gemm_k(
    const ushort* __restrict__ A, int lda,
    const ushort* __restrict__ Bt,
    const float* __restrict__ bias,
    const ushort* __restrict__ Rm, int ldr,
    ushort* __restrict__ C, int ldc) {
    __shared__ ushort As[128 * 64];
    __shared__ ushort Bs[128 * 64];
    int t = threadIdx.x, lane = t & 63, w = t >> 6;
    int row0 = blockIdx.x * 128, col0 = blockIdx.y * 128;
    int lrow = lane >> 3;                 // row within 8-row staging chunk
    int kx = ((lane & 7) ^ lrow) << 3;    // swizzled k element offset
    const ushort* gA = A + (size_t)(row0 + w * 32 + lrow) * lda + kx;
    const ushort* gB = Bt + (size_t)(col0 + w * 32 + lrow) * 256 + kx;
    f32x4 acc[4][4];
#pragma unroll
    for (int i = 0; i < 4; ++i)
#pragma unroll
        for (int j = 0; j < 4; ++j) acc[i][j] = (f32x4){0.f, 0.f, 0.f, 0.f};
    int wm = w >> 1, wn = w & 1;
    int mbase = wm * 64 + (lane & 15);
    int nbase = wn * 64 + (lane & 15);
    int l7 = lane & 7;
    for (int k0 = 0; k0 < 256; k0 += 64) {
        __syncthreads();
#pragma unroll
        for (int c2 = 0; c2 < 4; ++c2) {
            GLD16(gA + (size_t)(c2 * 8) * lda + k0, &As[(w * 4 + c2) * 512]);
            GLD16(gB + (size_t)(c2 * 8) * 256 + k0, &Bs[(w * 4 + c2) * 512]);
        }
        __syncthreads();
#pragma unroll
        for (int ks = 0; ks < 2; ++ks) {
            int kb = ks * 4 + (lane >> 4);
            bf16x8 af[4], bfr[4];
#pragma unroll
            for (int tm = 0; tm < 4; ++tm)
                af[tm] = *(const bf16x8*)&As[(mbase + tm * 16) * 64 + ((kb ^ l7) << 3)];
#pragma unroll
            for (int tn = 0; tn < 4; ++tn)
                bfr[tn] = *(const bf16x8*)&Bs[(nbase + tn * 16) * 64 + ((kb ^ l7) << 3)];
#pragma unroll
            for (int tm = 0; tm < 4; ++tm)
#pragma unroll
                for (int tn = 0; tn < 4; ++tn)
                    acc[tm][tn] = __builtin_amdgcn_mfma_f32_16x16x32_bf16(
                        af[tm], bfr[tn], acc[tm][tn], 0, 0, 0);
        }
    }
    int q = lane >> 4;
    int crow = row0 + wm * 64 + q * 4;
    int ccol = col0 + wn * 64 + (lane & 15);
#pragma unroll
    for (int tm = 0; tm < 4; ++tm)
#pragma unroll
        for (int r = 0; r < 4; ++r) {
            int row = crow + tm * 16 + r;
#pragma unroll
            for (int tn = 0; tn < 4; ++tn) {
                int col = ccol + tn * 16;
                float v = acc[tm][tn][r];
                if (BIAS) v += bias[col];
                if (RES) v += bf2f(Rm[(size_t)row * ldr + col]);
                C[(size_t)row * ldc + col] = f2bf(v);
            }
        }
}

// ---------------- attention (seq=2) on fused qkv [row,768] ----------------
__global__ __launch_bounds__(256) void attn_k(ushort* __restrict__ qkv) {
    int wid = threadIdx.x >> 6, lane = threadIdx.x & 63;
    int gw = blockIdx.x * 4 + wid;
    int p = gw >> 2, hh = gw & 3;
    size_t r0 = (size_t)(2 * p) * 768 + hh * 64 + lane;
    size_t r1 = r0 + 768;
    float q0 = bf2f(qkv[r0]) * 0.125f, q1 = bf2f(qkv[r1]) * 0.125f;
    float k0 = bf2f(qkv[r0 + 256]), k1 = bf2f(qkv[r1 + 256]);
    float v0 = bf2f(qkv[r0 + 512]), v1 = bf2f(qkv[r1 + 512]);
    float s00 = q0 * k0, s01 = q0 * k1, s10 = q1 * k0, s11 = q1 * k1;
#pragma unroll
    for (int off = 32; off; off >>= 1) {
        s00 += __shfl_xor(s00, off, 64);
        s01 += __shfl_xor(s01, off, 64);
        s10 += __shfl_xor(s10, off, 64);
        s11 += __shfl_xor(s11, off, 64);
    }
    float m0 = fmaxf(s00, s01), m1 = fmaxf(s10, s11);
    float e00 = expf(s00 - m0), e01 = expf(s01 - m0);
    float e10 = expf(s10 - m1), e11 = expf(s11 - m1);
    float i0 = 1.f / (e00 + e01), i1 = 1.f / (e10 + e11);
    float o0 = (e00 * i0) * v0 + (e01 * i0) * v1;
    float o1 = (e10 * i1) * v0 + (e11 * i1) * v1;
    qkv[r0] = f2bf(o0);
    qkv[r1] = f2bf(o1);
}

// ---------------- layernorms (wave per row, bf16 io) ----------------
__global__ __launch_bounds__(256) void ln_a_k(
    const ushort* __restrict__ X, int ldx, ushort* __restrict__ H,
    const float* __restrict__ sc, const float* __restrict__ bi) {
    int w = threadIdx.x >> 6, lane = threadIdx.x & 63;
    int r = blockIdx.x * 4 + w;
    int d0 = lane * 4;
    ushort4 xv = *(const ushort4*)&X[(size_t)r * ldx + d0];
    float x[4] = {bf2f(xv.x), bf2f(xv.y), bf2f(xv.z), bf2f(xv.w)};
    float sum = x[0] + x[1] + x[2] + x[3];
    float sq = x[0] * x[0] + x[1] * x[1] + x[2] * x[2] + x[3] * x[3];
#pragma unroll
    for (int off = 32; off; off >>= 1) {
        sum += __shfl_xor(sum, off, 64);
        sq += __shfl_xor(sq, off, 64);
    }
    float m = sum * (1.f / 256.f);
    float var = sq * (1.f / 256.f) - m * m;
    float rs = rsqrtf(var + 1e-5f);
    float4 s4 = *(const float4*)&sc[d0];
    float4 b4 = *(const float4*)&bi[d0];
    ushort4 o;
    o.x = f2bf((x[0] - m) * rs * s4.x + b4.x);
    o.y = f2bf((x[1] - m) * rs * s4.y + b4.y);
    o.z = f2bf((x[2] - m) * rs * s4.z + b4.z);
    o.w = f2bf((x[3] - m) * rs * s4.w + b4.w);
    *(ushort4*)&H[(size_t)r * 256 + d0] = o;
}

// H = LN(H + tanh(T)) in place
__global__ __launch_bounds__(256) void ln_b_k(
    ushort* __restrict__ H, const ushort* __restrict__ T,
    const float* __restrict__ sc, const float* __restrict__ bi) {
    int w = threadIdx.x >> 6, lane = threadIdx.x & 63;
    int r = blockIdx.x * 4 + w;
    int d0 = lane * 4;
    ushort4 hv = *(const ushort4*)&H[(size_t)r * 256 + d0];
    ushort4 tv = *(const ushort4*)&T[(size_t)r * 256 + d0];
    float x[4];
    x[0] = bf2f(hv.x) + tanhf(bf2f(tv.x));
    x[1] = bf2f(hv.y) + tanhf(bf2f(tv.y));
    x[2] = bf2f(hv.z) + tanhf(bf2f(tv.z));
    x[3] = bf2f(hv.w) + tanhf(bf2f(tv.w));
    float sum = x[0] + x[1] + x[2] + x[3];
    float sq = x[0] * x[0] + x[1] * x[1] + x[2] * x[2] + x[3] * x[3];
#pragma unroll
    for (int off = 32; off; off >>= 1) {
        sum += __shfl_xor(sum, off, 64);
        sq += __shfl_xor(sq, off, 64);
    }
    float m = sum * (1.f / 256.f);
    float var = sq * (1.f / 256.f) - m * m;
    float rs = rsqrtf(var + 1e-5f);
    float4 s4 = *(const float4*)&sc[d0];
    float4 b4 = *(const float4*)&bi[d0];
    ushort4 o;
    o.x = f2bf((x[0] - m) * rs * s4.x + b4.x);
    o.y = f2bf((x[1] - m) * rs * s4.y + b4.y);
    o.z = f2bf((x[2] - m) * rs * s4.z + b4.z);
    o.w = f2bf((x[3] - m) * rs * s4.w + b4.w);
    *(ushort4*)&H[(size_t)r * 256 + d0] = o;
}

// ---------------- per-pair orbitals + 2x2 det ----------------
__global__ __launch_bounds__(256) void orb_k(
    const ushort* __restrict__ h, const float* __restrict__ Wr, const float* __restrict__ Wi,
    const float* __restrict__ el, const int* __restrict__ ip, const int* __restrict__ jp,
    float2* __restrict__ porb, int P0) {
    int w = threadIdx.x >> 6, lane = threadIdx.x & 63;
    int p = blockIdx.x * 4 + w;
    const ushort* h0 = h + (size_t)(2 * p) * 256;
    int d0 = lane * 4;
    ushort4 a0 = *(const ushort4*)&h0[d0];
    ushort4 a1 = *(const ushort4*)&h0[256 + d0];
    float x0[4] = {bf2f(a0.x), bf2f(a0.y), bf2f(a0.z), bf2f(a0.w)};
    float x1[4] = {bf2f(a1.x), bf2f(a1.y), bf2f(a1.z), bf2f(a1.w)};
    float wrv[8], wiv[8];
    *(float4*)&wrv[0] = *(const float4*)&Wr[2 * d0];
    *(float4*)&wrv[4] = *(const float4*)&Wr[2 * d0 + 4];
    *(float4*)&wiv[0] = *(const float4*)&Wi[2 * d0];
    *(float4*)&wiv[4] = *(const float4*)&Wi[2 * d0 + 4];
    float s[8] = {0, 0, 0, 0, 0, 0, 0, 0};
#pragma unroll
    for (int u = 0; u < 4; ++u) {
        s[0] += x0[u] * wrv[2 * u];     s[1] += x0[u] * wiv[2 * u];
        s[2] += x0[u] * wrv[2 * u + 1]; s[3] += x0[u] * wiv[2 * u + 1];
        s[4] += x1[u] * wrv[2 * u];     s[5] += x1[u] * wiv[2 * u];
        s[6] += x1[u] * wrv[2 * u + 1]; s[7] += x1[u] * wiv[2 * u + 1];
    }
#pragma unroll
    for (int off = 32; off; off >>= 1) {
#pragma unroll
        for (int q2 = 0; q2 < 8; ++q2) s[q2] += __shfl_xor(s[q2], off, 64);
    }
    if (lane == 0) {
        int gp = P0 + p;
        int i = ip[gp], j = jp[gp];
        float thi = el[2 * i], phi_ = el[2 * i + 1];
        float thj = el[2 * j], phj = el[2 * j + 1];
        float chi = cosf(thi * 0.5f), shi = sinf(thi * 0.5f);
        float chj = cosf(thj * 0.5f), shj = sinf(thj * 0.5f);
        float cpi = cosf(phi_ * 0.5f), spi = sinf(phi_ * 0.5f);
        float cpj = cosf(phj * 0.5f), spj = sinf(phj * 0.5f);
        float uix = chi * cpi, uiy = chi * spi;
        float vix = shi * cpi, viy = -shi * spi;
        float ujx = chj * cpj, ujy = chj * spj;
        float vjx = shj * cpj, vjy = -shj * spj;
        float crx = (uix * vjx - uiy * vjy) - (ujx * vix - ujy * viy);
        float cry = (uix * vjy + uiy * vjx) - (ujx * viy + ujy * vix);
        float chord2 = crx * crx + cry * cry;
        float trunc = 1.f - expf(-100.f * chord2);
        float t2 = trunc * trunc;
        float dr = (s[0] * s[6] - s[1] * s[7]) - (s[2] * s[4] - s[3] * s[5]);
        float di = (s[0] * s[7] + s[1] * s[6]) - (s[2] * s[5] + s[3] * s[4]);
        porb[gp] = make_float2(dr * t2, di * t2);
    }
}

// ---------------- assemble A = pf + cusp, accumulate log_bos ----------------
__global__ __launch_bounds__(256) void assemble_k(
    const float* __restrict__ el, const float2* __restrict__ porb,
    float2* __restrict__ Am, float* acc) {
    __shared__ float sre[256], sim[256];
    int idx = blockIdx.x * 256 + threadIdx.x;
    int i = idx >> 8, j = idx & 255;
    float thi = el[2 * i], phi_ = el[2 * i + 1];
    float thj = el[2 * j], phj = el[2 * j + 1];
    float chi = cosf(thi * 0.5f), shi = sinf(thi * 0.5f);
    float chj = cosf(thj * 0.5f), shj = sinf(thj * 0.5f);
    float cpi = cosf(phi_ * 0.5f), spi = sinf(phi_ * 0.5f);
    float cpj = cosf(phj * 0.5f), spj = sinf(phj * 0.5f);
    float uix = chi * cpi, uiy = chi * spi;
    float vix = shi * cpi, viy = -shi * spi;
    float ujx = chj * cpj, ujy = chj * spj;
    float vjx = shj * cpj, vjy = -shj * spj;
    float ex = (uix * vjx - uiy * vjy) - (ujx * vix - ujy * viy);
    float ey = (uix * vjy + uiy * vjx) - (ujx * viy + ujy * vix);
    float pfx = 0.f, pfy = 0.f;
    if (i < j) {
        int pp = i * 255 - (i * (i - 1)) / 2 + (j - i - 1);
        float2 t = porb[pp]; pfx = t.x; pfy = t.y;
    } else if (i > j) {
        int pp = j * 255 - (j * (j - 1)) / 2 + (i - j - 1);
        float2 t = porb[pp]; pfx = -t.x; pfy = -t.y;
    }
    float eye = (i == j) ? 1.f : 0.f;
    float ecx = ex + eye, ecy = ey;
    float wgt = expf(-100.f * (ecx * ecx + ecy * ecy));
    Am[idx] = make_float2(pfx + ecx * wgt, pfy + ecy * wgt);
    float lre = 0.f, lim = 0.f;
    if (i != j) {
        float r2 = ex * ex + ey * ey;
        lre = 0.5f * logf(0.01f + r2);
        lim = atan2f(ey, ex);
    }
    sre[threadIdx.x] = lre; sim[threadIdx.x] = lim;
    __syncthreads();
    for (int s2 = 128; s2; s2 >>= 1) {
        if (threadIdx.x < s2) {
            sre[threadIdx.x] += sre[threadIdx.x + s2];
            sim[threadIdx.x] += sim[threadIdx.x + s2];
        }
        __syncthreads();
    }
    if (threadIdx.x == 0) {
        atomicAdd(acc + 0, sre[0]);
        atomicAdd(acc + 1, sim[0]);
    }
}

// ---------------- LU panel: 512 threads, 3 barriers/step, deferred logs ----------------
__global__ __launch_bounds__(512) void panel_k(
    float2* __restrict__ Am, int* __restrict__ pivg, float* __restrict__ acc, int k0) {
    __shared__ float2 Pn[256][NB + 1];
    __shared__ float rmax[8];
    __shared__ int rmaxi[8];
    __shared__ float2 diag_s[NB];
    __shared__ int nsw_s;
    int t = threadIdx.x, lane = t & 63, w = t >> 6;
    int nr = 256 - k0;
    for (int idx = t; idx < nr * NB; idx += 512)
        Pn[idx >> 5][idx & 31] = Am[(size_t)(k0 + (idx >> 5)) * NE + k0 + (idx & 31)];
    if (t == 0) nsw_s = 0;
    __syncthreads();
    for (int j = 0; j < NB; ++j) {
        if (t < 256) {
            float val = -1.f; int id = j;
            if (t >= j && t < nr) {
                float2 a = Pn[t][j];
                val = fabsf(a.x) + fabsf(a.y);
                id = t;
            }
#pragma unroll
            for (int off = 32; off; off >>= 1) {
                float ov = __shfl_xor(val, off, 64);
                int oi = __shfl_xor(id, off, 64);
                if (ov > val) { val = ov; id = oi; }
            }
            if (lane == 0) { rmax[w] = val; rmaxi[w] = id; }
        }
        __syncthreads();
        if (w == 0) {  // wave0 only: pivot pick, record, inv, swap — lockstep, no barrier
            float bv = rmax[0]; int bi = rmaxi[0];
            for (int q2 = 1; q2 < 4; ++q2)
                if (rmax[q2] > bv) { bv = rmax[q2]; bi = rmaxi[q2]; }
            float2 d = Pn[bi][j];  // broadcast read (pre-swap == post-swap diag)
            if (lane == 0) {
                diag_s[j] = d;
                pivg[j] = k0 + bi;
                if (bi != j) nsw_s++;
                float iv = 1.f / (d.x * d.x + d.y * d.y);
                rmax[4] = d.x * iv; rmax[5] = -d.y * iv;  // stash inv
            }
            if (bi != j && lane < NB) {
                float2 tmp = Pn[j][lane]; Pn[j][lane] = Pn[bi][lane]; Pn[bi][lane] = tmp;
            }
        }
        __syncthreads();
        float2 inv = make_float2(rmax[4], rmax[5]);
        int c = t & 31, rb = t >> 5;  // 16 rows in flight; row-group = half-wave (lockstep)
        float2 u = Pn[j][c];
        for (int r = j + 1 + rb; r < nr; r += 16) {
            float2 a = Pn[r][j];
            float2 L = make_float2(a.x * inv.x - a.y * inv.y, a.x * inv.y + a.y * inv.x);
            if (c == j) Pn[r][j] = L;
            else if (c > j) {
                float2 x = Pn[r][c];
                x.x -= L.x * u.x - L.y * u.y;
                x.y -= L.x * u.y + L.y * u.x;
                Pn[r][c] = x;
            }
        }
        __syncthreads();
    }
    for (int idx = t; idx < nr * NB; idx += 512)
        Am[(size_t)(k0 + (idx >> 5)) * NE + k0 + (idx & 31)] = Pn[idx >> 5][idx & 31];
    if (w == 0) {
        float lre = 0.f, lim = 0.f;
        if (lane < NB) {
            float2 d = diag_s[lane];
            lre = 0.5f * logf(d.x * d.x + d.y * d.y);
            lim = atan2f(d.y, d.x);
        }
#pragma unroll
        for (int off = 32; off; off >>= 1) {
            lre += __shfl_xor(lre, off, 64);
            lim += __shfl_xor(lim, off, 64);
        }
        if (lane == 0) { acc[2] += lre; acc[3] += lim; acc[4] += (float)nsw_s; }
    }
}

// trsm with fused trailing-column pivot swaps: thread per column
__global__ __launch_bounds__(256) void trsm_k(
    float2* __restrict__ Am, const int* __restrict__ pivg, int k0) {
    __shared__ float2 Ls[NB][NB + 1];
    __shared__ int pv[NB];
    int t = threadIdx.x;
    if (t < NB) pv[t] = pivg[t];
    for (int idx = t; idx < NB * NB; idx += 256)
        Ls[idx >> 5][idx & 31] = Am[(size_t)(k0 + (idx >> 5)) * NE + k0 + (idx & 31)];
    __syncthreads();
    int ncols = NE - k0 - NB;
    if (t >= ncols) return;
    int col = k0 + NB + t;
    for (int j = 0; j < NB; ++j) {  // laswp on this column
        int r2 = pv[j];
        if (r2 != k0 + j) {
            float2 a = Am[(size_t)(k0 + j) * NE + col];
            Am[(size_t)(k0 + j) * NE + col] = Am[(size_t)r2 * NE + col];
            Am[(size_t)r2 * NE + col] = a;
        }
    }
    float2 x[NB];
#pragma unroll
    for (int i = 0; i < NB; ++i) x[i] = Am[(size_t)(k0 + i) * NE + col];
#pragma unroll
    for (int i = 1; i < NB; ++i) {
        float2 xi = x[i];
#pragma unroll
        for (int j = 0; j < i; ++j) {
            float2 l = Ls[i][j];
            xi.x -= l.x * x[j].x - l.y * x[j].y;
            xi.y -= l.x * x[j].y + l.y * x[j].x;
        }
        x[i] = xi;
    }
#pragma unroll
    for (int i = 1; i < NB; ++i) Am[(size_t)(k0 + i) * NE + col] = x[i];
}

// A22 -= L21 @ U12, complex, K=NB. 32x32 tile per block.
__global__ __launch_bounds__(256) void update_k(float2* __restrict__ Am, int k0) {
    __shared__ float2 Lt[NB][NB + 1];
    __shared__ float2 Ut[NB][NB + 1];
    int t = threadIdx.x;
    int r0 = k0 + NB + blockIdx.x * NB;
    int c0 = k0 + NB + blockIdx.y * NB;
    for (int idx = t; idx < NB * NB; idx += 256) {
        int a = idx >> 5, b = idx & 31;
        Lt[a][b] = Am[(size_t)(r0 + a) * NE + k0 + b];
        Ut[a][b] = Am[(size_t)(k0 + a) * NE + c0 + b];
    }
    __syncthreads();
    int lr = t >> 3, lc0 = (t & 7) * 4;
    float2 s0 = {0.f, 0.f}, s1 = {0.f, 0.f}, s2 = {0.f, 0.f}, s3 = {0.f, 0.f};
#pragma unroll
    for (int k = 0; k < NB; ++k) {
        float2 a = Lt[lr][k];
        float2 u0 = Ut[k][lc0 + 0], u1 = Ut[k][lc0 + 1];
        float2 u2 = Ut[k][lc0 + 2], u3 = Ut[k][lc0 + 3];
        s0.x += a.x * u0.x - a.y * u0.y; s0.y += a.x * u0.y + a.y * u0.x;
        s1.x += a.x * u1.x - a.y * u1.y; s1.y += a.x * u1.y + a.y * u1.x;
        s2.x += a.x * u2.x - a.y * u2.y; s2.y += a.x * u2.y + a.y * u2.x;
        s3.x += a.x * u3.x - a.y * u3.y; s3.y += a.x * u3.y + a.y * u3.x;
    }
    size_t base = (size_t)(r0 + lr) * NE + c0 + lc0;
    float2 cc;
    cc = Am[base + 0]; cc.x -= s0.x; cc.y -= s0.y; Am[base + 0] = cc;
    cc = Am[base + 1]; cc.x -= s1.x; cc.y -= s1.y; Am[base + 1] = cc;
    cc = Am[base + 2]; cc.x -= s2.x; cc.y -= s2.y; Am[base + 2] = cc;
    cc = Am[base + 3]; cc.x -= s3.x; cc.y -= s3.y; Am[base + 3] = cc;
}

__global__ void finalize_k(const float* __restrict__ acc, float* __restrict__ out) {
    if (threadIdx.x == 0) {
        float ang = acc[3] + 3.14159265358979323846f * acc[4];
        ang -= 6.283185307179586f * rintf(ang * 0.15915494309189535f);
        out[0] = 0.5f * acc[2] + acc[0];
        out[1] = 0.5f * ang + acc[1];
    }
}

// ---------------- host launch ----------------
extern "C" void kernel_launch(void* const* d_in, const int* in_sizes, int n_in,
                              void* d_out, int out_size, void* d_ws, size_t ws_size,
                              hipStream_t stream) {
    (void)in_sizes; (void)n_in; (void)out_size;
    const float* el   = (const float*)d_in[0];
    const float* Win  = (const float*)d_in[1];
    const float* Wq   = (const float*)d_in[2];
    const float* bq   = (const float*)d_in[3];
    const float* Wk   = (const float*)d_in[4];
    const float* bk   = (const float*)d_in[5];
    const float* Wv   = (const float*)d_in[6];
    const float* bv   = (const float*)d_in[7];
    const float* Wo   = (const float*)d_in[8];
    const float* bo   = (const float*)d_in[9];
    const float* W1   = (const float*)d_in[10];
    const float* ln1s = (const float*)d_in[11];
    const float* ln1b = (const float*)d_in[12];
    const float* W2   = (const float*)d_in[13];
    const float* b2   = (const float*)d_in[14];
    const float* ln2s = (const float*)d_in[15];
    const float* ln2b = (const float*)d_in[16];
    const float* Wor  = (const float*)d_in[17];
    const float* Woi  = (const float*)d_in[18];

    char* wp = (char*)d_ws;
    auto alloc = [&](size_t b) {
        char* r = wp;
        wp += (b + 255) & ~(size_t)255;
        return r;
    };
    int*    ipb  = (int*)alloc((size_t)P_TOT * 4);
    int*    jpb  = (int*)alloc((size_t)P_TOT * 4);
    float2* porb = (float2*)alloc((size_t)P_TOT * 8);
    float2* Am   = (float2*)alloc((size_t)NE * NE * 8);
    float*  acc  = (float*)alloc(256);
    int*    pivg = (int*)alloc((size_t)NE * 4);
    ushort* Wqkv_t = (ushort*)alloc((size_t)2 * 768 * 256 * 2);
    ushort* Woth_t = (ushort*)alloc((size_t)6 * 65536 * 2);
    float*  bqkv = (float*)alloc((size_t)2 * 768 * 4);
    ushort* hb   = (ushort*)alloc((size_t)MC * 256 * 2);
    ushort* qkvb = (ushort*)alloc((size_t)MC * 768 * 2);
    ushort* tb   = (ushort*)alloc((size_t)MC * 256 * 2);
    size_t need = (size_t)(wp - (char*)d_ws);
    if (need > ws_size) {
        zero_k<<<1, 64, 0, stream>>>((float*)d_out);
        return;
    }

    prep_w_k<<<dim3(8, 8, 12), 256, 0, stream>>>(Wq, Wk, Wv, Wo, W1, W2, Wqkv_t, Woth_t);
    prep_b_k<<<2, 256, 0, stream>>>(bq, bk, bv, bqkv);
    idx_k<<<1, 256, 0, stream>>>(ipb, jpb);
    zero_k<<<1, 64, 0, stream>>>(acc);

    for (int c = 0; c < NCHUNK; ++c) {
        int P0 = c * PC;
        embed_k<<<MC / 4, 256, 0, stream>>>(el, Win, ipb, jpb, hb, P0);
        for (int l = 0; l < NL; ++l) {
            gemm_k<true, false><<<dim3(MT, 6), 256, 0, stream>>>(
                hb, 256, Wqkv_t + (size_t)l * 768 * 256, bqkv + l * 768, nullptr, 0, qkvb, 768);
            attn_k<<<PC, 256, 0, stream>>>(qkvb);
            gemm_k<true, false><<<dim3(MT, 2), 256, 0, stream>>>(
                qkvb, 768, Woth_t + (size_t)(l * 3 + 0) * 65536, bo + l * 256, nullptr, 0, tb, 256);
            gemm_k<false, true><<<dim3(MT, 2), 256, 0, stream>>>(
                tb, 256, Woth_t + (size_t)(l * 3 + 1) * 65536, nullptr, hb, 256, qkvb, 768);
            ln_a_k<<<MC / 4, 256, 0, stream>>>(qkvb, 768, hb, ln1s + l * 256, ln1b + l * 256);
            gemm_k<true, false><<<dim3(MT, 2), 256, 0, stream>>>(
                hb, 256, Woth_t + (size_t)(l * 3 + 2) * 65536, b2 + l * 256, nullptr, 0, tb, 256);
            ln_b_k<<<MC / 4, 256, 0, stream>>>(hb, tb, ln2s + l * 256, ln2b + l * 256);
        }
        orb_k<<<PC / 4, 256, 0, stream>>>(hb, Wor, Woi, el, ipb, jpb, porb, P0);
    }
    assemble_k<<<NE, 256, 0, stream>>>(el, porb, Am, acc);

    for (int p = 0; p < NPANEL; ++p) {
        int k0 = p * NB;
        panel_k<<<1, 512, 0, stream>>>(Am, pivg + p * NB, acc, k0);
        int m = NE - k0 - NB;
        if (m > 0) {
            trsm_k<<<1, 256, 0, stream>>>(Am, pivg + p * NB, k0);
            dim3 ug(m / NB, m / NB);
            update_k<<<ug, 256, 0, stream>>>(Am, k0);
        }
    }
    finalize_k<<<1, 64, 0, stream>>>(acc, (float*)d_out);
}

// Round 4
// 1228.011 us; speedup vs baseline: 3.6629x; 1.1246x over previous
//
// R4: register-resident LU panel (a[32] in VGPRs, fully unrolled, 2 barriers/step),
//     trsm with composed-permutation gather (no serial global swap chain).
//     Transformer unchanged from R3 (bf16 MFMA 128x128 GEMMs, fused QKV).
#include <hip/hip_runtime.h>
#include <math.h>
#include <stdint.h>

#define NE 256
#define DD 256
#define NL 2
#define P_TOT 32640          // NE*(NE-1)/2
#define NCHUNK 3
#define PC (P_TOT / NCHUNK)  // 10880 pairs per chunk
#define MC (2 * PC)          // 21760 rows = 170*128
#define MT (MC / 128)        // 170
#define NB 32                // LU panel width
#define NPANEL (NE / NB)

typedef __bf16 bf16x8 __attribute__((ext_vector_type(8)));
typedef float f32x4 __attribute__((ext_vector_type(4)));

__device__ __forceinline__ float bf2f(ushort h) {
    union { unsigned u; float f; } c; c.u = ((unsigned)h) << 16; return c.f;
}
__device__ __forceinline__ ushort f2bf(float f) {
    union { float f; unsigned u; } c; c.f = f;
    unsigned u = c.u;
    return (ushort)((u + 0x7fffu + ((u >> 16) & 1u)) >> 16);
}

#define GLD16(gp, lp) __builtin_amdgcn_global_load_lds( \
    (const __attribute__((address_space(1))) unsigned int*)(uintptr_t)(gp), \
    (__attribute__((address_space(3))) unsigned int*)(uintptr_t)(lp), 16, 0, 0)

// ---------------- small helpers ----------------
__global__ void idx_k(int* __restrict__ ip, int* __restrict__ jp) {
    int i = threadIdx.x;  // 0..255
    int base = i * 255 - (i * (i - 1)) / 2;
    for (int j = i + 1; j < NE; ++j) {
        ip[base + j - i - 1] = i;
        jp[base + j - i - 1] = j;
    }
}

__global__ void zero_k(float* __restrict__ acc) {
    if (threadIdx.x < 8) acc[threadIdx.x] = 0.f;
}

// ---------------- weight prep: Bt[n][k] = W[k][n] in bf16 ----------------
__global__ __launch_bounds__(256) void prep_w_k(
    const float* __restrict__ Wq, const float* __restrict__ Wk, const float* __restrict__ Wv,
    const float* __restrict__ Wo, const float* __restrict__ W1, const float* __restrict__ W2,
    ushort* __restrict__ Wqkv_t, ushort* __restrict__ Woth_t) {
    __shared__ float Ts[32][33];
    int z = blockIdx.z, l = z / 6, m = z % 6;
    const float* src;
    ushort* dst;
    if (m == 0)      { src = Wq + l * 65536; dst = Wqkv_t + (size_t)l * 768 * 256 + 0 * 65536; }
    else if (m == 1) { src = Wk + l * 65536; dst = Wqkv_t + (size_t)l * 768 * 256 + 1 * 65536; }
    else if (m == 2) { src = Wv + l * 65536; dst = Wqkv_t + (size_t)l * 768 * 256 + 2 * 65536; }
    else             { src = (m == 3 ? Wo : m == 4 ? W1 : W2) + l * 65536;
                       dst = Woth_t + (size_t)(l * 3 + (m - 3)) * 65536; }
    int k0 = blockIdx.x * 32, n0 = blockIdx.y * 32;
    int t = threadIdx.x, tr = t >> 5, tc = t & 31;
    for (int i = tr; i < 32; i += 8) Ts[i][tc] = src[(size_t)(k0 + i) * 256 + n0 + tc];
    __syncthreads();
    for (int i = tr; i < 32; i += 8) dst[(size_t)(n0 + i) * 256 + k0 + tc] = f2bf(Ts[tc][i]);
}

__global__ void prep_b_k(const float* __restrict__ bq, const float* __restrict__ bk,
                         const float* __restrict__ bv, float* __restrict__ bqkv) {
    int l = blockIdx.x, t = threadIdx.x;
    bqkv[l * 768 + t] = bq[l * 256 + t];
    bqkv[l * 768 + 256 + t] = bk[l * 256 + t];
    bqkv[l * 768 + 512 + t] = bv[l * 256 + t];
}

// ---------------- embedding: h = feat @ W_in (bf16 out) ----------------
__global__ __launch_bounds__(256) void embed_k(
    const float* __restrict__ el, const float* __restrict__ Win,
    const int* __restrict__ ip, const int* __restrict__ jp,
    ushort* __restrict__ h, int P0) {
    int w = threadIdx.x >> 6, lane = threadIdx.x & 63;
    int r = blockIdx.x * 4 + w;
    int gp = P0 + (r >> 1);
    int e = (r & 1) ? jp[gp] : ip[gp];
    float th = el[2 * e], ph = el[2 * e + 1];
    float st = sinf(th);
    float f0 = cosf(th), f1 = st * cosf(ph), f2 = st * sinf(ph);
    int n = lane * 4;
    float4 w0 = *(const float4*)&Win[n];
    float4 w1 = *(const float4*)&Win[256 + n];
    float4 w2 = *(const float4*)&Win[512 + n];
    ushort4 o;
    o.x = f2bf(f0 * w0.x + f1 * w1.x + f2 * w2.x);
    o.y = f2bf(f0 * w0.y + f1 * w1.y + f2 * w2.y);
    o.z = f2bf(f0 * w0.z + f1 * w1.z + f2 * w2.z);
    o.w = f2bf(f0 * w0.w + f1 * w1.w + f2 * w2.w);
    *(ushort4*)&h[(size_t)r * 256 + n] = o;
}

// ---------------- bf16 MFMA GEMM: C = A@B (+bias) (+residual) ----------------
template <bool BIAS, bool RES>
__global__ __launch_bounds__(256) void gemm_k(
    const ushort* __restrict__ A, int lda,
    const ushort* __restrict__ Bt,
    const float* __restrict__ bias,
    const ushort* __restrict__ Rm, int ldr,
    ushort* __restrict__ C, int ldc) {
    __shared__ ushort As[128 * 64];
    __shared__ ushort Bs[128 * 64];
    int t = threadIdx.x, lane = t & 63, w = t >> 6;
    int row0 = blockIdx.x * 128, col0 = blockIdx.y * 128;
    int lrow = lane >> 3;                 // row within 8-row staging chunk
    int kx = ((lane & 7) ^ lrow) << 3;    // swizzled k element offset
    const ushort* gA = A + (size_t)(row0 + w * 32 + lrow) * lda + kx;
    const ushort* gB = Bt + (size_t)(col0 + w * 32 + lrow) * 256 + kx;
    f32x4 acc[4][4];
#pragma unroll
    for (int i = 0; i < 4; ++i)
#pragma unroll
        for (int j = 0; j < 4; ++j) acc[i][j] = (f32x4){0.f, 0.f, 0.f, 0.f};
    int wm = w >> 1, wn = w & 1;
    int mbase = wm * 64 + (lane & 15);
    int nbase = wn * 64 + (lane & 15);
    int l7 = lane & 7;
    for (int k0 = 0; k0 < 256; k0 += 64) {
        __syncthreads();
#pragma unroll
        for (int c2 = 0; c2 < 4; ++c2) {
            GLD16(gA + (size_t)(c2 * 8) * lda + k0, &As[(w * 4 + c2) * 512]);
            GLD16(gB + (size_t)(c2 * 8) * 256 + k0, &Bs[(w * 4 + c2) * 512]);
        }
        __syncthreads();
#pragma unroll
        for (int ks = 0; ks < 2; ++ks) {
            int kb = ks * 4 + (lane >> 4);
            bf16x8 af[4], bfr[4];
#pragma unroll
            for (int tm = 0; tm < 4; ++tm)
                af[tm] = *(const bf16x8*)&As[(mbase + tm * 16) * 64 + ((kb ^ l7) << 3)];
#pragma unroll
            for (int tn = 0; tn < 4; ++tn)
                bfr[tn] = *(const bf16x8*)&Bs[(nbase + tn * 16) * 64 + ((kb ^ l7) << 3)];
#pragma unroll
            for (int tm = 0; tm < 4; ++tm)
#pragma unroll
                for (int tn = 0; tn < 4; ++tn)
                    acc[tm][tn] = __builtin_amdgcn_mfma_f32_16x16x32_bf16(
                        af[tm], bfr[tn], acc[tm][tn], 0, 0, 0);
        }
    }
    int q = lane >> 4;
    int crow = row0 + wm * 64 + q * 4;
    int ccol = col0 + wn * 64 + (lane & 15);
#pragma unroll
    for (int tm = 0; tm < 4; ++tm)
#pragma unroll
        for (int r = 0; r < 4; ++r) {
            int row = crow + tm * 16 + r;
#pragma unroll
            for (int tn = 0; tn < 4; ++tn) {
                int col = ccol + tn * 16;
                float v = acc[tm][tn][r];
                if (BIAS) v += bias[col];
                if (RES) v += bf2f(Rm[(size_t)row * ldr + col]);
                C[(size_t)row * ldc + col] = f2bf(v);
            }
        }
}

// ---------------- attention (seq=2) on fused qkv [row,768] ----------------
__global__ __launch_bounds__(256) void attn_k(ushort* __restrict__ qkv) {
    int wid = threadIdx.x >> 6, lane = threadIdx.x & 63;
    int gw = blockIdx.x * 4 + wid;
    int p = gw >> 2, hh = gw & 3;
    size_t r0 = (size_t)(2 * p) * 768 + hh * 64 + lane;
    size_t r1 = r0 + 768;
    float q0 = bf2f(qkv[r0]) * 0.125f, q1 = bf2f(qkv[r1]) * 0.125f;
    float k0 = bf2f(qkv[r0 + 256]), k1 = bf2f(qkv[r1 + 256]);
    float v0 = bf2f(qkv[r0 + 512]), v1 = bf2f(qkv[r1 + 512]);
    float s00 = q0 * k0, s01 = q0 * k1, s10 = q1 * k0, s11 = q1 * k1;
#pragma unroll
    for (int off = 32; off; off >>= 1) {
        s00 += __shfl_xor(s00, off, 64);
        s01 += __shfl_xor(s01, off, 64);
        s10 += __shfl_xor(s10, off, 64);
        s11 += __shfl_xor(s11, off, 64);
    }
    float m0 = fmaxf(s00, s01), m1 = fmaxf(s10, s11);
    float e00 = expf(s00 - m0), e01 = expf(s01 - m0);
    float e10 = expf(s10 - m1), e11 = expf(s11 - m1);
    float i0 = 1.f / (e00 + e01), i1 = 1.f / (e10 + e11);
    float o0 = (e00 * i0) * v0 + (e01 * i0) * v1;
    float o1 = (e10 * i1) * v0 + (e11 * i1) * v1;
    qkv[r0] = f2bf(o0);
    qkv[r1] = f2bf(o1);
}

// ---------------- layernorms (wave per row, bf16 io) ----------------
__global__ __launch_bounds__(256) void ln_a_k(
    const ushort* __restrict__ X, int ldx, ushort* __restrict__ H,
    const float* __restrict__ sc, const float* __restrict__ bi) {
    int w = threadIdx.x >> 6, lane = threadIdx.x & 63;
    int r = blockIdx.x * 4 + w;
    int d0 = lane * 4;
    ushort4 xv = *(const ushort4*)&X[(size_t)r * ldx + d0];
    float x[4] = {bf2f(xv.x), bf2f(xv.y), bf2f(xv.z), bf2f(xv.w)};
    float sum = x[0] + x[1] + x[2] + x[3];
    float sq = x[0] * x[0] + x[1] * x[1] + x[2] * x[2] + x[3] * x[3];
#pragma unroll
    for (int off = 32; off; off >>= 1) {
        sum += __shfl_xor(sum, off, 64);
        sq += __shfl_xor(sq, off, 64);
    }
    float m = sum * (1.f / 256.f);
    float var = sq * (1.f / 256.f) - m * m;
    float rs = rsqrtf(var + 1e-5f);
    float4 s4 = *(const float4*)&sc[d0];
    float4 b4 = *(const float4*)&bi[d0];
    ushort4 o;
    o.x = f2bf((x[0] - m) * rs * s4.x + b4.x);
    o.y = f2bf((x[1] - m) * rs * s4.y + b4.y);
    o.z = f2bf((x[2] - m) * rs * s4.z + b4.z);
    o.w = f2bf((x[3] - m) * rs * s4.w + b4.w);
    *(ushort4*)&H[(size_t)r * 256 + d0] = o;
}

// H = LN(H + tanh(T)) in place
__global__ __launch_bounds__(256) void ln_b_k(
    ushort* __restrict__ H, const ushort* __restrict__ T,
    const float* __restrict__ sc, const float* __restrict__ bi) {
    int w = threadIdx.x >> 6, lane = threadIdx.x & 63;
    int r = blockIdx.x * 4 + w;
    int d0 = lane * 4;
    ushort4 hv = *(const ushort4*)&H[(size_t)r * 256 + d0];
    ushort4 tv = *(const ushort4*)&T[(size_t)r * 256 + d0];
    float x[4];
    x[0] = bf2f(hv.x) + tanhf(bf2f(tv.x));
    x[1] = bf2f(hv.y) + tanhf(bf2f(tv.y));
    x[2] = bf2f(hv.z) + tanhf(bf2f(tv.z));
    x[3] = bf2f(hv.w) + tanhf(bf2f(tv.w));
    float sum = x[0] + x[1] + x[2] + x[3];
    float sq = x[0] * x[0] + x[1] * x[1] + x[2] * x[2] + x[3] * x[3];
#pragma unroll
    for (int off = 32; off; off >>= 1) {
        sum += __shfl_xor(sum, off, 64);
        sq += __shfl_xor(sq, off, 64);
    }
    float m = sum * (1.f / 256.f);
    float var = sq * (1.f / 256.f) - m * m;
    float rs = rsqrtf(var + 1e-5f);
    float4 s4 = *(const float4*)&sc[d0];
    float4 b4 = *(const float4*)&bi[d0];
    ushort4 o;
    o.x = f2bf((x[0] - m) * rs * s4.x + b4.x);
    o.y = f2bf((x[1] - m) * rs * s4.y + b4.y);
    o.z = f2bf((x[2] - m) * rs * s4.z + b4.z);
    o.w = f2bf((x[3] - m) * rs * s4.w + b4.w);
    *(ushort4*)&H[(size_t)r * 256 + d0] = o;
}

// ---------------- per-pair orbitals + 2x2 det ----------------
__global__ __launch_bounds__(256) void orb_k(
    const ushort* __restrict__ h, const float* __restrict__ Wr, const float* __restrict__ Wi,
    const float* __restrict__ el, const int* __restrict__ ip, const int* __restrict__ jp,
    float2* __restrict__ porb, int P0) {
    int w = threadIdx.x >> 6, lane = threadIdx.x & 63;
    int p = blockIdx.x * 4 + w;
    const ushort* h0 = h + (size_t)(2 * p) * 256;
    int d0 = lane * 4;
    ushort4 a0 = *(const ushort4*)&h0[d0];
    ushort4 a1 = *(const ushort4*)&h0[256 + d0];
    float x0[4] = {bf2f(a0.x), bf2f(a0.y), bf2f(a0.z), bf2f(a0.w)};
    float x1[4] = {bf2f(a1.x), bf2f(a1.y), bf2f(a1.z), bf2f(a1.w)};
    float wrv[8], wiv[8];
    *(float4*)&wrv[0] = *(const float4*)&Wr[2 * d0];
    *(float4*)&wrv[4] = *(const float4*)&Wr[2 * d0 + 4];
    *(float4*)&wiv[0] = *(const float4*)&Wi[2 * d0];
    *(float4*)&wiv[4] = *(const float4*)&Wi[2 * d0 + 4];
    float s[8] = {0, 0, 0, 0, 0, 0, 0, 0};
#pragma unroll
    for (int u = 0; u < 4; ++u) {
        s[0] += x0[u] * wrv[2 * u];     s[1] += x0[u] * wiv[2 * u];
        s[2] += x0[u] * wrv[2 * u + 1]; s[3] += x0[u] * wiv[2 * u + 1];
        s[4] += x1[u] * wrv[2 * u];     s[5] += x1[u] * wiv[2 * u];
        s[6] += x1[u] * wrv[2 * u + 1]; s[7] += x1[u] * wiv[2 * u + 1];
    }
#pragma unroll
    for (int off = 32; off; off >>= 1) {
#pragma unroll
        for (int q2 = 0; q2 < 8; ++q2) s[q2] += __shfl_xor(s[q2], off, 64);
    }
    if (lane == 0) {
        int gp = P0 + p;
        int i = ip[gp], j = jp[gp];
        float thi = el[2 * i], phi_ = el[2 * i + 1];
        float thj = el[2 * j], phj = el[2 * j + 1];
        float chi = cosf(thi * 0.5f), shi = sinf(thi * 0.5f);
        float chj = cosf(thj * 0.5f), shj = sinf(thj * 0.5f);
        float cpi = cosf(phi_ * 0.5f), spi = sinf(phi_ * 0.5f);
        float cpj = cosf(phj * 0.5f), spj = sinf(phj * 0.5f);
        float uix = chi * cpi, uiy = chi * spi;
        float vix = shi * cpi, viy = -shi * spi;
        float ujx = chj * cpj, ujy = chj * spj;
        float vjx = shj * cpj, vjy = -shj * spj;
        float crx = (uix * vjx - uiy * vjy) - (ujx * vix - ujy * viy);
        float cry = (uix * vjy + uiy * vjx) - (ujx * viy + ujy * vix);
        float chord2 = crx * crx + cry * cry;
        float trunc = 1.f - expf(-100.f * chord2);
        float t2 = trunc * trunc;
        float dr = (s[0] * s[6] - s[1] * s[7]) - (s[2] * s[4] - s[3] * s[5]);
        float di = (s[0] * s[7] + s[1] * s[6]) - (s[2] * s[5] + s[3] * s[4]);
        porb[gp] = make_float2(dr * t2, di * t2);
    }
}

// ---------------- assemble A = pf + cusp, accumulate log_bos ----------------
__global__ __launch_bounds__(256) void assemble_k(
    const float* __restrict__ el, const float2* __restrict__ porb,
    float2* __restrict__ Am, float* acc) {
    __shared__ float sre[256], sim[256];
    int idx = blockIdx.x * 256 + threadIdx.x;
    int i = idx >> 8, j = idx & 255;
    float thi = el[2 * i], phi_ = el[2 * i + 1];
    float thj = el[2 * j], phj = el[2 * j + 1];
    float chi = cosf(thi * 0.5f), shi = sinf(thi * 0.5f);
    float chj = cosf(thj * 0.5f), shj = sinf(thj * 0.5f);
    float cpi = cosf(phi_ * 0.5f), spi = sinf(phi_ * 0.5f);
    float cpj = cosf(phj * 0.5f), spj = sinf(phj * 0.5f);
    float uix = chi * cpi, uiy = chi * spi;
    float vix = shi * cpi, viy = -shi * spi;
    float ujx = chj * cpj, ujy = chj * spj;
    float vjx = shj * cpj, vjy = -shj * spj;
    float ex = (uix * vjx - uiy * vjy) - (ujx * vix - ujy * viy);
    float ey = (uix * vjy + uiy * vjx) - (ujx * viy + ujy * vix);
    float pfx = 0.f, pfy = 0.f;
    if (i < j) {
        int pp = i * 255 - (i * (i - 1)) / 2 + (j - i - 1);
        float2 t = porb[pp]; pfx = t.x; pfy = t.y;
    } else if (i > j) {
        int pp = j * 255 - (j * (j - 1)) / 2 + (i - j - 1);
        float2 t = porb[pp]; pfx = -t.x; pfy = -t.y;
    }
    float eye = (i == j) ? 1.f : 0.f;
    float ecx = ex + eye, ecy = ey;
    float wgt = expf(-100.f * (ecx * ecx + ecy * ecy));
    Am[idx] = make_float2(pfx + ecx * wgt, pfy + ecy * wgt);
    float lre = 0.f, lim = 0.f;
    if (i != j) {
        float r2 = ex * ex + ey * ey;
        lre = 0.5f * logf(0.01f + r2);
        lim = atan2f(ey, ex);
    }
    sre[threadIdx.x] = lre; sim[threadIdx.x] = lim;
    __syncthreads();
    for (int s2 = 128; s2; s2 >>= 1) {
        if (threadIdx.x < s2) {
            sre[threadIdx.x] += sre[threadIdx.x + s2];
            sim[threadIdx.x] += sim[threadIdx.x + s2];
        }
        __syncthreads();
    }
    if (threadIdx.x == 0) {
        atomicAdd(acc + 0, sre[0]);
        atomicAdd(acc + 1, sim[0]);
    }
}

// ---------------- LU panel v3: rows in registers, 2 barriers/step ----------------
// Thread t owns local row t of the 256xNB panel in regs. Fully unrolled so all
// register indices are static (no scratch).
__global__ __launch_bounds__(256) void panel_k(
    float2* __restrict__ Am, int* __restrict__ pivg, float* __restrict__ acc, int k0) {
    __shared__ float rbest[2][4];
    __shared__ int ribest[2][4];
    __shared__ float2 bufA[2][NB];   // outgoing row j
    __shared__ float2 bufB[2][NB];   // pivot row (becomes new row j / the U row)
    __shared__ float2 diag_s[NB];
    int t = threadIdx.x, lane = t & 63, w = t >> 6;
    int nr = NE - k0;
    bool act = t < nr;
    float2 a[NB];
    if (act) {
        const float2* src = Am + (size_t)(k0 + t) * NE + k0;
#pragma unroll
        for (int c = 0; c < NB; ++c) a[c] = src[c];
    }
    int nsw = 0;
#pragma unroll
    for (int j = 0; j < NB; ++j) {
        const int par = j & 1;
        // --- pivot argmax over column j (registers + shuffles) ---
        float val = (act && t >= j) ? (fabsf(a[j].x) + fabsf(a[j].y)) : -1.f;
        int id = t;
#pragma unroll
        for (int off = 32; off; off >>= 1) {
            float ov = __shfl_xor(val, off, 64);
            int oi = __shfl_xor(id, off, 64);
            if (ov > val) { val = ov; id = oi; }
        }
        if (lane == 0) { rbest[par][w] = val; ribest[par][w] = id; }
        __syncthreads();
        float bv = rbest[par][0]; int piv = ribest[par][0];
#pragma unroll
        for (int q = 1; q < 4; ++q) {
            float v2 = rbest[par][q];
            if (v2 > bv) { bv = v2; piv = ribest[par][q]; }
        }
        // --- swap rows j <-> piv through LDS ---
        if (t == j) {
#pragma unroll
            for (int c = 0; c < NB; ++c) bufA[par][c] = a[c];
        }
        if (t == piv) {
#pragma unroll
            for (int c = 0; c < NB; ++c) bufB[par][c] = a[c];
        }
        __syncthreads();
        if (t == j) {
#pragma unroll
            for (int c = 0; c < NB; ++c) a[c] = bufB[par][c];
        } else if (t == piv) {
#pragma unroll
            for (int c = 0; c < NB; ++c) a[c] = bufA[par][c];
        }
        float2 d = bufB[par][j];
        if (t == 0) {
            diag_s[j] = d;
            pivg[j] = k0 + piv;
            if (piv != j) nsw++;
        }
        float ivn = 1.f / (d.x * d.x + d.y * d.y);
        float2 inv = make_float2(d.x * ivn, -d.y * ivn);
        // --- eliminate: pure register FMAs, LDS broadcast U reads ---
        if (act && t > j) {
            float2 L = make_float2(a[j].x * inv.x - a[j].y * inv.y,
                                   a[j].x * inv.y + a[j].y * inv.x);
            a[j] = L;
#pragma unroll
            for (int c = j + 1; c < NB; ++c) {
                float2 u = bufB[par][c];
                a[c].x -= L.x * u.x - L.y * u.y;
                a[c].y -= L.x * u.y + L.y * u.x;
            }
        }
    }
    if (act) {
        float2* dst = Am + (size_t)(k0 + t) * NE + k0;
#pragma unroll
        for (int c = 0; c < NB; ++c) dst[c] = a[c];
    }
    __syncthreads();
    if (w == 0) {
        float lre = 0.f, lim = 0.f;
        if (lane < NB) {
            float2 d = diag_s[lane];
            lre = 0.5f * logf(d.x * d.x + d.y * d.y);
            lim = atan2f(d.y, d.x);
        }
#pragma unroll
        for (int off = 32; off; off >>= 1) {
            lre += __shfl_xor(lre, off, 64);
            lim += __shfl_xor(lim, off, 64);
        }
        if (lane == 0) { acc[2] += lre; acc[3] += lim; }
    }
    if (t == 0) acc[4] += (float)nsw;
}

// ---------------- trsm v3: composed-permutation gather + register solve ----------------
__global__ __launch_bounds__(256) void trsm_k(
    float2* __restrict__ Am, const int* __restrict__ pivg, int k0) {
    __shared__ float2 Ls[NB][NB + 1];
    __shared__ short sigma[NE];
    __shared__ short rlist[NB];
    __shared__ int rcount;
    int t = threadIdx.x;
    sigma[t] = (short)t;
    for (int idx = t; idx < NB * NB; idx += 256)
        Ls[idx >> 5][idx & 31] = Am[(size_t)(k0 + (idx >> 5)) * NE + k0 + (idx & 31)];
    if (t < NB) rlist[t] = (short)k0;  // dummy default (valid row, never stored)
    __syncthreads();
    if (t == 0) {
        for (int j = 0; j < NB; ++j) {
            int p = pivg[j], r1 = k0 + j;
            short tmp = sigma[r1]; sigma[r1] = sigma[p]; sigma[p] = tmp;
        }
        int cnt = 0;
        for (int r = k0 + NB; r < NE; ++r)
            if (sigma[r] != r) rlist[cnt++] = (short)r;
        rcount = cnt;
    }
    __syncthreads();
    int ncols = NE - k0 - NB;
    if (t >= ncols) return;
    int col = k0 + NB + t;
    int cnt = rcount;
    // gather panel-top rows (post-permutation) — independent loads
    float2 x[NB];
#pragma unroll
    for (int i = 0; i < NB; ++i)
        x[i] = Am[(size_t)sigma[k0 + i] * NE + col];
    // gather displaced below-panel rows — independent loads
    float2 extra[NB];
#pragma unroll
    for (int q = 0; q < NB; ++q)
        extra[q] = Am[(size_t)sigma[rlist[q]] * NE + col];
    // unit-lower triangular solve, registers + LDS broadcast
#pragma unroll
    for (int i = 1; i < NB; ++i) {
        float2 xi = x[i];
#pragma unroll
        for (int j = 0; j < i; ++j) {
            float2 l = Ls[i][j];
            xi.x -= l.x * x[j].x - l.y * x[j].y;
            xi.y -= l.x * x[j].y + l.y * x[j].x;
        }
        x[i] = xi;
    }
    // stores (after all loads): U12 rows and permuted below-panel rows
#pragma unroll
    for (int i = 0; i < NB; ++i)
        Am[(size_t)(k0 + i) * NE + col] = x[i];
#pragma unroll
    for (int q = 0; q < NB; ++q)
        if (q < cnt) Am[(size_t)rlist[q] * NE + col] = extra[q];
}

// A22 -= L21 @ U12, complex, K=NB. 32x32 tile per block.
__global__ __launch_bounds__(256) void update_k(float2* __restrict__ Am, int k0) {
    __shared__ float2 Lt[NB][NB + 1];
    __shared__ float2 Ut[NB][NB + 1];
    int t = threadIdx.x;
    int r0 = k0 + NB + blockIdx.x * NB;
    int c0 = k0 + NB + blockIdx.y * NB;
    for (int idx = t; idx < NB * NB; idx += 256) {
        int a = idx >> 5, b = idx & 31;
        Lt[a][b] = Am[(size_t)(r0 + a) * NE + k0 + b];
        Ut[a][b] = Am[(size_t)(k0 + a) * NE + c0 + b];
    }
    __syncthreads();
    int lr = t >> 3, lc0 = (t & 7) * 4;
    float2 s0 = {0.f, 0.f}, s1 = {0.f, 0.f}, s2 = {0.f, 0.f}, s3 = {0.f, 0.f};
#pragma unroll
    for (int k = 0; k < NB; ++k) {
        float2 a = Lt[lr][k];
        float2 u0 = Ut[k][lc0 + 0], u1 = Ut[k][lc0 + 1];
        float2 u2 = Ut[k][lc0 + 2], u3 = Ut[k][lc0 + 3];
        s0.x += a.x * u0.x - a.y * u0.y; s0.y += a.x * u0.y + a.y * u0.x;
        s1.x += a.x * u1.x - a.y * u1.y; s1.y += a.x * u1.y + a.y * u1.x;
        s2.x += a.x * u2.x - a.y * u2.y; s2.y += a.x * u2.y + a.y * u2.x;
        s3.x += a.x * u3.x - a.y * u3.y; s3.y += a.x * u3.y + a.y * u3.x;
    }
    size_t base = (size_t)(r0 + lr) * NE + c0 + lc0;
    float2 cc;
    cc = Am[base + 0]; cc.x -= s0.x; cc.y -= s0.y; Am[base + 0] = cc;
    cc = Am[base + 1]; cc.x -= s1.x; cc.y -= s1.y; Am[base + 1] = cc;
    cc = Am[base + 2]; cc.x -= s2.x; cc.y -= s2.y; Am[base + 2] = cc;
    cc = Am[base + 3]; cc.x -= s3.x; cc.y -= s3.y; Am[base + 3] = cc;
}

__global__ void finalize_k(const float* __restrict__ acc, float* __restrict__ out) {
    if (threadIdx.x == 0) {
        float ang = acc[3] + 3.14159265358979323846f * acc[4];
        ang -= 6.283185307179586f * rintf(ang * 0.15915494309189535f);
        out[0] = 0.5f * acc[2] + acc[0];
        out[1] = 0.5f * ang + acc[1];
    }
}

// ---------------- host launch ----------------
extern "C" void kernel_launch(void* const* d_in, const int* in_sizes, int n_in,
                              void* d_out, int out_size, void* d_ws, size_t ws_size,
                              hipStream_t stream) {
    (void)in_sizes; (void)n_in; (void)out_size;
    const float* el   = (const float*)d_in[0];
    const float* Win  = (const float*)d_in[1];
    const float* Wq   = (const float*)d_in[2];
    const float* bq   = (const float*)d_in[3];
    const float* Wk   = (const float*)d_in[4];
    const float* bk   = (const float*)d_in[5];
    const float* Wv   = (const float*)d_in[6];
    const float* bv   = (const float*)d_in[7];
    const float* Wo   = (const float*)d_in[8];
    const float* bo   = (const float*)d_in[9];
    const float* W1   = (const float*)d_in[10];
    const float* ln1s = (const float*)d_in[11];
    const float* ln1b = (const float*)d_in[12];
    const float* W2   = (const float*)d_in[13];
    const float* b2   = (const float*)d_in[14];
    const float* ln2s = (const float*)d_in[15];
    const float* ln2b = (const float*)d_in[16];
    const float* Wor  = (const float*)d_in[17];
    const float* Woi  = (const float*)d_in[18];

    char* wp = (char*)d_ws;
    auto alloc = [&](size_t b) {
        char* r = wp;
        wp += (b + 255) & ~(size_t)255;
        return r;
    };
    int*    ipb  = (int*)alloc((size_t)P_TOT * 4);
    int*    jpb  = (int*)alloc((size_t)P_TOT * 4);
    float2* porb = (float2*)alloc((size_t)P_TOT * 8);
    float2* Am   = (float2*)alloc((size_t)NE * NE * 8);
    float*  acc  = (float*)alloc(256);
    int*    pivg = (int*)alloc((size_t)NE * 4);
    ushort* Wqkv_t = (ushort*)alloc((size_t)2 * 768 * 256 * 2);
    ushort* Woth_t = (ushort*)alloc((size_t)6 * 65536 * 2);
    float*  bqkv = (float*)alloc((size_t)2 * 768 * 4);
    ushort* hb   = (ushort*)alloc((size_t)MC * 256 * 2);
    ushort* qkvb = (ushort*)alloc((size_t)MC * 768 * 2);
    ushort* tb   = (ushort*)alloc((size_t)MC * 256 * 2);
    size_t need = (size_t)(wp - (char*)d_ws);
    if (need > ws_size) {
        zero_k<<<1, 64, 0, stream>>>((float*)d_out);
        return;
    }

    prep_w_k<<<dim3(8, 8, 12), 256, 0, stream>>>(Wq, Wk, Wv, Wo, W1, W2, Wqkv_t, Woth_t);
    prep_b_k<<<2, 256, 0, stream>>>(bq, bk, bv, bqkv);
    idx_k<<<1, 256, 0, stream>>>(ipb, jpb);
    zero_k<<<1, 64, 0, stream>>>(acc);

    for (int c = 0; c < NCHUNK; ++c) {
        int P0 = c * PC;
        embed_k<<<MC / 4, 256, 0, stream>>>(el, Win, ipb, jpb, hb, P0);
        for (int l = 0; l < NL; ++l) {
            gemm_k<true, false><<<dim3(MT, 6), 256, 0, stream>>>(
                hb, 256, Wqkv_t + (size_t)l * 768 * 256, bqkv + l * 768, nullptr, 0, qkvb, 768);
            attn_k<<<PC, 256, 0, stream>>>(qkvb);
            gemm_k<true, false><<<dim3(MT, 2), 256, 0, stream>>>(
                qkvb, 768, Woth_t + (size_t)(l * 3 + 0) * 65536, bo + l * 256, nullptr, 0, tb, 256);
            gemm_k<false, true><<<dim3(MT, 2), 256, 0, stream>>>(
                tb, 256, Woth_t + (size_t)(l * 3 + 1) * 65536, nullptr, hb, 256, qkvb, 768);
            ln_a_k<<<MC / 4, 256, 0, stream>>>(qkvb, 768, hb, ln1s + l * 256, ln1b + l * 256);
            gemm_k<true, false><<<dim3(MT, 2), 256, 0, stream>>>(
                hb, 256, Woth_t + (size_t)(l * 3 + 2) * 65536, b2 + l * 256, nullptr, 0, tb, 256);
            ln_b_k<<<MC / 4, 256, 0, stream>>>(hb, tb, ln2s + l * 256, ln2b + l * 256);
        }
        orb_k<<<PC / 4, 256, 0, stream>>>(hb, Wor, Woi, el, ipb, jpb, porb, P0);
    }
    assemble_k<<<NE, 256, 0, stream>>>(el, porb, Am, acc);

    for (int p = 0; p < NPANEL; ++p) {
        int k0 = p * NB;
        panel_k<<<1, 256, 0, stream>>>(Am, pivg + p * NB, acc, k0);
        int m = NE - k0 - NB;
        if (m > 0) {
            trsm_k<<<1, 256, 0, stream>>>(Am, pivg + p * NB, k0);
            dim3 ug(m / NB, m / NB);
            update_k<<<ug, 256, 0, stream>>>(Am, k0);
        }
    }
    finalize_k<<<1, 64, 0, stream>>>(acc, (float*)d_out);
}